// Round 1
// baseline (1681.808 us; speedup 1.0000x reference)
//
#include <hip/hip_runtime.h>
#include <hip/hip_bf16.h>
#include <math.h>

#define N_NODES 50000
#define N_EDGES 800000
#define ET (N_EDGES + N_NODES)
#define HTOT 400

// layer input widths (= output column base) and output widths
__constant__ int c_dummy; // keep compiler happy if unused

static const int INS_h[4] = {16, 80, 144, 272};
static const int HO_h[4]  = {64, 64, 128, 128};

// ---------------- CSR build ----------------

__global__ void copy_x_kernel(const float* __restrict__ x, float* __restrict__ h) {
    int i = blockIdx.x * blockDim.x + threadIdx.x;
    if (i >= N_NODES * 16) return;
    int n = i >> 4, c = i & 15;
    h[n * HTOT + c] = x[i];
}

__global__ void hist_kernel(const int* __restrict__ ei, int* __restrict__ deg) {
    int e = blockIdx.x * blockDim.x + threadIdx.x;
    if (e >= ET) return;
    int dst = (e < N_EDGES) ? ei[N_EDGES + e] : (e - N_EDGES);
    atomicAdd(&deg[dst], 1);
}

__global__ __launch_bounds__(1024) void scan_kernel(const int* __restrict__ deg,
                                                    int* __restrict__ row_ptr,
                                                    int* __restrict__ cursor) {
    __shared__ int sums[1024];
    int t = threadIdx.x;
    const int CH = (N_NODES + 1023) / 1024;
    int beg = t * CH, end = min(beg + CH, N_NODES);
    int s = 0;
    for (int i = beg; i < end; ++i) s += deg[i];
    sums[t] = s;
    __syncthreads();
    for (int off = 1; off < 1024; off <<= 1) {
        int v2 = (t >= off) ? sums[t - off] : 0;
        __syncthreads();
        sums[t] += v2;
        __syncthreads();
    }
    int excl = (t == 0) ? 0 : sums[t - 1];
    for (int i = beg; i < end; ++i) {
        row_ptr[i] = excl;
        cursor[i] = excl;
        excl += deg[i];
    }
    if (t == 0) row_ptr[N_NODES] = sums[1023];
}

__global__ void scatter_kernel(const int* __restrict__ ei, int* __restrict__ cursor,
                               int* __restrict__ col_src) {
    int e = blockIdx.x * blockDim.x + threadIdx.x;
    if (e >= ET) return;
    int src, dst;
    if (e < N_EDGES) { src = ei[e]; dst = ei[N_EDGES + e]; }
    else             { src = dst = e - N_EDGES; }
    int p = atomicAdd(&cursor[dst], 1);
    col_src[p] = src;
}

// ---------------- fp32 GEMM: C[M x fo] = A[M x K (lda)] * W[K x fo] (+bias) ----------------
// 64x64 block tile, 256 threads, 4x4 micro-tile per thread.

__global__ __launch_bounds__(256) void gemm_kernel(
    const float* __restrict__ A, int lda,
    const float* __restrict__ W,
    const float* __restrict__ bias,
    float* __restrict__ C, int ldc,
    int M, int K, int fo) {
    int r0 = blockIdx.x * 64, c0 = blockIdx.y * 64;
    int tx = threadIdx.x & 15, ty = threadIdx.x >> 4;
    float acc[4][4] = {};
    int rr[4];
    bool rv[4];
#pragma unroll
    for (int i = 0; i < 4; ++i) { rr[i] = r0 + ty + 16 * i; rv[i] = rr[i] < M; }
    for (int k = 0; k < K; k += 4) {
        float hk[4][4];
#pragma unroll
        for (int i = 0; i < 4; ++i) {
            float4 t4 = rv[i] ? *reinterpret_cast<const float4*>(&A[(size_t)rr[i] * lda + k])
                              : make_float4(0.f, 0.f, 0.f, 0.f);
            hk[i][0] = t4.x; hk[i][1] = t4.y; hk[i][2] = t4.z; hk[i][3] = t4.w;
        }
#pragma unroll
        for (int kk = 0; kk < 4; ++kk) {
            float wv[4];
#pragma unroll
            for (int j = 0; j < 4; ++j) wv[j] = W[(size_t)(k + kk) * fo + c0 + tx + 16 * j];
#pragma unroll
            for (int i = 0; i < 4; ++i)
#pragma unroll
                for (int j = 0; j < 4; ++j) acc[i][j] = fmaf(hk[i][kk], wv[j], acc[i][j]);
        }
    }
#pragma unroll
    for (int i = 0; i < 4; ++i) {
        if (!rv[i]) continue;
#pragma unroll
        for (int j = 0; j < 4; ++j) {
            int c = c0 + tx + 16 * j;
            float b = bias ? bias[c] : 0.f;
            C[(size_t)rr[i] * ldc + c] = acc[i][j] + b;
        }
    }
}

// ---------------- attention: one wave per node, lanes = channels ----------------

template <int CPL>
__global__ __launch_bounds__(256) void attn_kernel(
    float* __restrict__ h,
    const float* __restrict__ aS, const float* __restrict__ aD, const float* __restrict__ vbuf,
    const float* __restrict__ Wp, const float* __restrict__ bp,
    const int* __restrict__ row_ptr, const int* __restrict__ col_src,
    int colbase) {
    constexpr int FO = 64 * CPL;
    int wid = (blockIdx.x * blockDim.x + threadIdx.x) >> 6;
    if (wid >= N_NODES) return;
    int lane = threadIdx.x & 63;
    int n = wid;
    float px = h[(size_t)n * HTOT + 0];
    float py = h[(size_t)n * HTOT + 1];
    float pz = h[(size_t)n * HTOT + 2];
    float wp0[CPL], wp1[CPL], wp2[CPL], bpv[CPL], ad[CPL];
    float m[CPL], s[CPL], num[CPL];
#pragma unroll
    for (int j = 0; j < CPL; ++j) {
        int c = lane + 64 * j;
        wp0[j] = Wp[c];
        wp1[j] = Wp[FO + c];
        wp2[j] = Wp[2 * FO + c];
        bpv[j] = bp[c];
        ad[j] = aD[(size_t)n * FO + c];
        m[j] = -INFINITY; s[j] = 0.f; num[j] = 0.f;
    }
    int beg = row_ptr[n], end = row_ptr[n + 1];
    for (int i = beg; i < end; ++i) {
        int src = col_src[i];
        float dx = px - h[(size_t)src * HTOT + 0];
        float dy = py - h[(size_t)src * HTOT + 1];
        float dz = pz - h[(size_t)src * HTOT + 2];
#pragma unroll
        for (int j = 0; j < CPL; ++j) {
            int c = lane + 64 * j;
            float delta = fmaf(dx, wp0[j], fmaf(dy, wp1[j], fmaf(dz, wp2[j], bpv[j])));
            float alpha = ad[j] - aS[(size_t)src * FO + c] + delta;
            float val = vbuf[(size_t)src * FO + c] + delta;
            if (alpha > m[j]) {
                float sc = __expf(m[j] - alpha);
                s[j] *= sc;
                num[j] *= sc;
                m[j] = alpha;
            }
            float p = __expf(alpha - m[j]);
            s[j] += p;
            num[j] = fmaf(p, val, num[j]);
        }
    }
#pragma unroll
    for (int j = 0; j < CPL; ++j) {
        float xi = num[j] / s[j];
        xi = xi > 0.f ? xi : 0.01f * xi;
        h[(size_t)n * HTOT + colbase + lane + 64 * j] = xi;
    }
}

// ---------------- final tiny MLP layer 2 ----------------

__global__ void mlp2_kernel(const float* __restrict__ m1, const float* __restrict__ W,
                            const float* __restrict__ b, float* __restrict__ out) {
    int i = blockIdx.x * blockDim.x + threadIdx.x;
    if (i >= N_NODES * 8) return;
    int n = i >> 3, o = i & 7;
    float acc = b[o];
#pragma unroll 8
    for (int k = 0; k < 64; ++k) acc = fmaf(m1[(size_t)n * 64 + k], W[k * 8 + o], acc);
    out[i] = acc;
}

// ---------------- launch ----------------

extern "C" void kernel_launch(void* const* d_in, const int* in_sizes, int n_in,
                              void* d_out, int out_size, void* d_ws, size_t ws_size,
                              hipStream_t stream) {
    const float* x = (const float*)d_in[0];
    const int* ei = (const int*)d_in[1];
    const float *Wl[4], *Ws[4], *Wd[4], *Wp[4], *bp[4];
    for (int i = 0; i < 4; ++i) {
        Wl[i] = (const float*)d_in[2 + 5 * i];
        Ws[i] = (const float*)d_in[3 + 5 * i];
        Wd[i] = (const float*)d_in[4 + 5 * i];
        Wp[i] = (const float*)d_in[5 + 5 * i];
        bp[i] = (const float*)d_in[6 + 5 * i];
    }
    const float* Wm1 = (const float*)d_in[22];
    const float* bm1 = (const float*)d_in[23];
    const float* Wm2 = (const float*)d_in[24];
    const float* bm2 = (const float*)d_in[25];
    float* out = (float*)d_out;

    char* ws = (char*)d_ws;
    size_t off = 0;
    auto alloc = [&](size_t bytes) -> void* {
        void* p = ws + off;
        off += (bytes + 255) & ~(size_t)255;
        return p;
    };
    float* h = (float*)alloc((size_t)N_NODES * HTOT * 4);
    float* aS = (float*)alloc((size_t)N_NODES * 128 * 4);
    float* aD = (float*)alloc((size_t)N_NODES * 128 * 4);
    float* vb = (float*)alloc((size_t)N_NODES * 128 * 4);
    float* m1 = (float*)alloc((size_t)N_NODES * 64 * 4);
    int* deg = (int*)alloc((size_t)N_NODES * 4);
    int* rowp = (int*)alloc((size_t)(N_NODES + 1) * 4);
    int* cursor = (int*)alloc((size_t)N_NODES * 4);
    int* colsrc = (int*)alloc((size_t)ET * 4);
    (void)ws_size; (void)n_in; (void)in_sizes; (void)out_size;

    hipMemsetAsync(deg, 0, (size_t)N_NODES * 4, stream);
    copy_x_kernel<<<(N_NODES * 16 + 255) / 256, 256, 0, stream>>>(x, h);
    hist_kernel<<<(ET + 255) / 256, 256, 0, stream>>>(ei, deg);
    scan_kernel<<<1, 1024, 0, stream>>>(deg, rowp, cursor);
    scatter_kernel<<<(ET + 255) / 256, 256, 0, stream>>>(ei, cursor, colsrc);

    const int M = N_NODES;
    for (int L = 0; L < 4; ++L) {
        int K = INS_h[L], fo = HO_h[L];
        dim3 g((M + 63) / 64, fo / 64);
        gemm_kernel<<<g, 256, 0, stream>>>(h, HTOT, Ws[L], nullptr, aS, fo, M, K, fo);
        gemm_kernel<<<g, 256, 0, stream>>>(h, HTOT, Wd[L], nullptr, aD, fo, M, K, fo);
        gemm_kernel<<<g, 256, 0, stream>>>(h, HTOT, Wl[L], nullptr, vb, fo, M, K, fo);
        if (fo == 64)
            attn_kernel<1><<<(N_NODES + 3) / 4, 256, 0, stream>>>(h, aS, aD, vb, Wp[L], bp[L],
                                                                  rowp, colsrc, K);
        else
            attn_kernel<2><<<(N_NODES + 3) / 4, 256, 0, stream>>>(h, aS, aD, vb, Wp[L], bp[L],
                                                                  rowp, colsrc, K);
    }
    dim3 gm((M + 63) / 64, 1);
    gemm_kernel<<<gm, 256, 0, stream>>>(h, HTOT, Wm1, bm1, m1, 64, M, HTOT, 64);
    mlp2_kernel<<<(N_NODES * 8 + 255) / 256, 256, 0, stream>>>(m1, Wm2, bm2, out);
}

// Round 2
// 982.609 us; speedup vs baseline: 1.7116x; 1.7116x over previous
//
#include <hip/hip_runtime.h>
#include <hip/hip_bf16.h>
#include <math.h>

#define N_NODES 50000
#define N_EDGES 800000
#define ET (N_EDGES + N_NODES)
#define HTOT 400

typedef float f4 __attribute__((ext_vector_type(4)));
typedef float f2 __attribute__((ext_vector_type(2)));

static const int INS_h[4] = {16, 80, 144, 272};
static const int HO_h[4]  = {64, 64, 128, 128};

// ---------------- CSR build ----------------

__global__ void copy_x_kernel(const float* __restrict__ x, float* __restrict__ h) {
    int i = blockIdx.x * blockDim.x + threadIdx.x;
    if (i >= N_NODES * 16) return;
    int n = i >> 4, c = i & 15;
    h[n * HTOT + c] = x[i];
}

__global__ void hist_kernel(const int* __restrict__ ei, int* __restrict__ deg) {
    int e = blockIdx.x * blockDim.x + threadIdx.x;
    if (e >= ET) return;
    int dst = (e < N_EDGES) ? ei[N_EDGES + e] : (e - N_EDGES);
    atomicAdd(&deg[dst], 1);
}

__global__ __launch_bounds__(1024) void scan_kernel(const int* __restrict__ deg,
                                                    int* __restrict__ row_ptr,
                                                    int* __restrict__ cursor) {
    __shared__ int sums[1024];
    int t = threadIdx.x;
    const int CH = (N_NODES + 1023) / 1024;
    int beg = t * CH, end = min(beg + CH, N_NODES);
    int s = 0;
    for (int i = beg; i < end; ++i) s += deg[i];
    sums[t] = s;
    __syncthreads();
    for (int off = 1; off < 1024; off <<= 1) {
        int v2 = (t >= off) ? sums[t - off] : 0;
        __syncthreads();
        sums[t] += v2;
        __syncthreads();
    }
    int excl = (t == 0) ? 0 : sums[t - 1];
    for (int i = beg; i < end; ++i) {
        row_ptr[i] = excl;
        cursor[i] = excl;
        excl += deg[i];
    }
    if (t == 0) row_ptr[N_NODES] = sums[1023];
}

__global__ void scatter_kernel(const int* __restrict__ ei, const float* __restrict__ x,
                               int* __restrict__ cursor, float4* __restrict__ edata) {
    int e = blockIdx.x * blockDim.x + threadIdx.x;
    if (e >= ET) return;
    int src, dst;
    if (e < N_EDGES) { src = ei[e]; dst = ei[N_EDGES + e]; }
    else             { src = dst = e - N_EDGES; }
    int p = atomicAdd(&cursor[dst], 1);
    float dx = x[dst * 16 + 0] - x[src * 16 + 0];
    float dy = x[dst * 16 + 1] - x[src * 16 + 1];
    float dz = x[dst * 16 + 2] - x[src * 16 + 2];
    edata[p] = make_float4(__int_as_float(src), dx, dy, dz);
}

// ---------------- weight concat: Wcat[K][3fo] = [Ws | Wd | Wl] ----------------

__global__ void concat_w_kernel(const float* __restrict__ W0, const float* __restrict__ W1,
                                const float* __restrict__ W2, int K, int fo,
                                float* __restrict__ Wcat) {
    int i = blockIdx.x * blockDim.x + threadIdx.x;
    int n3 = 3 * fo;
    if (i >= K * n3) return;
    int k = i / n3, c = i - k * n3;
    const float* s;
    int cc;
    if (c < fo)          { s = W0; cc = c; }
    else if (c < 2 * fo) { s = W1; cc = c - fo; }
    else                 { s = W2; cc = c - 2 * fo; }
    Wcat[i] = s[k * fo + cc];
}

// ---------------- fp32 GEMM, double-buffered LDS, 128x64 tile ----------------
// C[M x N] = A[M x K (lda)] * W[K x N (ldw)].  K multiple of 16, N multiple of 64.
// FUSE: N==64, gridDim.y==1; epilogue computes out = (C+bias) @ W2 + b2 (64->8).

template <bool FUSE>
__global__ __launch_bounds__(256) void gemm2_kernel(
    const float* __restrict__ A, int lda,
    const float* __restrict__ W, int ldw,
    const float* __restrict__ bias,
    float* __restrict__ C, int ldc,
    int M, int K,
    const float* __restrict__ W2, const float* __restrict__ b2,
    float* __restrict__ out) {
    __shared__ float smem[9216];           // 36 KB: [2][128][20] A + [2][16][68] W; reused for FUSE epilogue
    float* sA = smem;                       // buf stride 2560
    float* sW = smem + 5120;                // buf stride 1088
    const int t = threadIdx.x;
    const int tx = t & 15, ty = t >> 4;
    const int r0 = blockIdx.x * 128;
    const int c0 = blockIdx.y * 64;

    f4 acc[8];
#pragma unroll
    for (int i = 0; i < 8; ++i) acc[i] = (f4){0.f, 0.f, 0.f, 0.f};

    const int arow = t >> 2;                // 0..63
    const int aq = (t & 3) * 4;             // 0,4,8,12
    const int wrow = t >> 4;                // 0..15
    const int wq = (t & 15) * 4;            // 0..60
    const int ar1 = min(r0 + arow, M - 1);
    const int ar2 = min(r0 + arow + 64, M - 1);

    const int nk = K >> 4;
    f4 ga0, ga1, gw;
    ga0 = *(const f4*)&A[(size_t)ar1 * lda + aq];
    ga1 = *(const f4*)&A[(size_t)ar2 * lda + aq];
    gw  = *(const f4*)&W[(size_t)wrow * ldw + c0 + wq];
    *(f4*)&sA[arow * 20 + aq] = ga0;
    *(f4*)&sA[(arow + 64) * 20 + aq] = ga1;
    *(f4*)&sW[wrow * 68 + wq] = gw;
    __syncthreads();

    int buf = 0;
    for (int kc = 0; kc < nk; ++kc) {
        const bool nx = (kc + 1) < nk;
        if (nx) {
            const int kb = (kc + 1) * 16;
            ga0 = *(const f4*)&A[(size_t)ar1 * lda + kb + aq];
            ga1 = *(const f4*)&A[(size_t)ar2 * lda + kb + aq];
            gw  = *(const f4*)&W[(size_t)(kb + wrow) * ldw + c0 + wq];
        }
        const float* bA = &sA[buf * 2560];
        const float* bW = &sW[buf * 1088];
#pragma unroll
        for (int k4 = 0; k4 < 4; ++k4) {
            f4 wv[4];
#pragma unroll
            for (int u = 0; u < 4; ++u)
                wv[u] = *(const f4*)&bW[(k4 * 4 + u) * 68 + tx * 4];
#pragma unroll
            for (int i = 0; i < 8; ++i) {
                f4 av = *(const f4*)&bA[(ty + 16 * i) * 20 + k4 * 4];
                acc[i] += av.x * wv[0];
                acc[i] += av.y * wv[1];
                acc[i] += av.z * wv[2];
                acc[i] += av.w * wv[3];
            }
        }
        if (nx) {
            const int ob = (buf ^ 1);
            *(f4*)&sA[ob * 2560 + arow * 20 + aq] = ga0;
            *(f4*)&sA[ob * 2560 + (arow + 64) * 20 + aq] = ga1;
            *(f4*)&sW[ob * 1088 + wrow * 68 + wq] = gw;
        }
        __syncthreads();
        buf ^= 1;
    }

    if (!FUSE) {
#pragma unroll
        for (int i = 0; i < 8; ++i) {
            int row = r0 + ty + 16 * i;
            if (row < M)
                *(f4*)&C[(size_t)row * ldc + c0 + tx * 4] = acc[i];
        }
    } else {
        // stage C tile (+bias) into smem, W2 alongside, then 64->8 MLP
        f4 bv = *(const f4*)&bias[c0 + tx * 4];
#pragma unroll
        for (int i = 0; i < 8; ++i)
            *(f4*)&smem[(ty + 16 * i) * 68 + tx * 4] = acc[i] + bv;
        smem[8704 + t] = W2[t];
        smem[8704 + 256 + t] = W2[256 + t];
        __syncthreads();
        const int row = t >> 1, oc = (t & 1) * 4;
        f4 o = *(const f4*)&b2[oc];
        const float* sC = smem;
        const float* sW2 = smem + 8704;
#pragma unroll 8
        for (int k = 0; k < 64; ++k) {
            float a = sC[row * 68 + k];
            o += a * *(const f4*)&sW2[k * 8 + oc];
        }
        const int grow = r0 + row;
        if (grow < M) *(f4*)&out[(size_t)grow * 8 + oc] = o;
    }
}

// ---------------- attention: one wave per node, lanes cover channels ----------------
// asdv layout: [n][3*FO]: cols [0,FO)=a_src, [FO,2FO)=a_dst, [2FO,3FO)=v

template <int CPL>
__global__ __launch_bounds__(256) void attn_kernel(
    float* __restrict__ h,
    const float* __restrict__ asdv,
    const float* __restrict__ Wp, const float* __restrict__ bp,
    const int* __restrict__ rowp, const float4* __restrict__ edata,
    int colbase) {
    constexpr int FO = 64 * CPL, LD = 3 * FO;
    int wid = (blockIdx.x * blockDim.x + threadIdx.x) >> 6;
    if (wid >= N_NODES) return;
    const int lane = threadIdx.x & 63;
    const int n = wid;
    const int cb = CPL * lane;
    float wp0[CPL], wp1[CPL], wp2[CPL], bpv[CPL], ad[CPL], m[CPL], s[CPL], num[CPL];
#pragma unroll
    for (int j = 0; j < CPL; ++j) {
        int c = cb + j;
        wp0[j] = Wp[c];
        wp1[j] = Wp[FO + c];
        wp2[j] = Wp[2 * FO + c];
        bpv[j] = bp[c];
        ad[j] = asdv[(size_t)n * LD + FO + c];
        m[j] = -INFINITY; s[j] = 0.f; num[j] = 0.f;
    }
    const int beg = rowp[n], end = rowp[n + 1];
    float4 ed = edata[beg];                  // degree >= 1 (self-loop)
    for (int i = beg; i < end; ++i) {
        float4 cur = ed;
        if (i + 1 < end) ed = edata[i + 1];
        const int src = __float_as_int(cur.x);
        const float* rs = &asdv[(size_t)src * LD];
#pragma unroll
        for (int j = 0; j < CPL; ++j) {
            int c = cb + j;
            float as = rs[c];
            float vv = rs[2 * FO + c];
            float delta = fmaf(cur.y, wp0[j], fmaf(cur.z, wp1[j], fmaf(cur.w, wp2[j], bpv[j])));
            float alpha = ad[j] - as + delta;
            float mn = fmaxf(m[j], alpha);
            float e0 = __expf(m[j] - mn);
            float p = __expf(alpha - mn);
            s[j] = s[j] * e0 + p;
            num[j] = num[j] * e0 + p * (vv + delta);
            m[j] = mn;
        }
    }
#pragma unroll
    for (int j = 0; j < CPL; ++j) {
        float xi = num[j] / s[j];
        xi = xi > 0.f ? xi : 0.01f * xi;
        h[(size_t)n * HTOT + colbase + cb + j] = xi;
    }
}

// ---------------- launch ----------------

extern "C" void kernel_launch(void* const* d_in, const int* in_sizes, int n_in,
                              void* d_out, int out_size, void* d_ws, size_t ws_size,
                              hipStream_t stream) {
    const float* x = (const float*)d_in[0];
    const int* ei = (const int*)d_in[1];
    const float *Wl[4], *Ws[4], *Wd[4], *Wp[4], *bp[4];
    for (int i = 0; i < 4; ++i) {
        Wl[i] = (const float*)d_in[2 + 5 * i];
        Ws[i] = (const float*)d_in[3 + 5 * i];
        Wd[i] = (const float*)d_in[4 + 5 * i];
        Wp[i] = (const float*)d_in[5 + 5 * i];
        bp[i] = (const float*)d_in[6 + 5 * i];
    }
    const float* Wm1 = (const float*)d_in[22];
    const float* bm1 = (const float*)d_in[23];
    const float* Wm2 = (const float*)d_in[24];
    const float* bm2 = (const float*)d_in[25];
    float* out = (float*)d_out;

    char* ws = (char*)d_ws;
    size_t off = 0;
    auto alloc = [&](size_t bytes) -> void* {
        void* p = ws + off;
        off += (bytes + 255) & ~(size_t)255;
        return p;
    };
    float* h = (float*)alloc((size_t)N_NODES * HTOT * 4);        // 80 MB
    float* asdv = (float*)alloc((size_t)N_NODES * 384 * 4);      // 76.8 MB
    float* Wcat = (float*)alloc((size_t)272 * 384 * 4);          // 417 KB
    int* deg = (int*)alloc((size_t)N_NODES * 4);
    int* rowp = (int*)alloc((size_t)(N_NODES + 1) * 4);
    int* cursor = (int*)alloc((size_t)N_NODES * 4);
    float4* edata = (float4*)alloc((size_t)ET * 16);             // 13.6 MB
    (void)ws_size; (void)n_in; (void)in_sizes; (void)out_size;

    hipMemsetAsync(deg, 0, (size_t)N_NODES * 4, stream);
    copy_x_kernel<<<(N_NODES * 16 + 255) / 256, 256, 0, stream>>>(x, h);
    hist_kernel<<<(ET + 255) / 256, 256, 0, stream>>>(ei, deg);
    scan_kernel<<<1, 1024, 0, stream>>>(deg, rowp, cursor);
    scatter_kernel<<<(ET + 255) / 256, 256, 0, stream>>>(ei, x, cursor, edata);

    const int M = N_NODES;
    const int gx = (M + 127) / 128;
    for (int L = 0; L < 4; ++L) {
        const int K = INS_h[L], fo = HO_h[L], n3 = 3 * fo;
        concat_w_kernel<<<(K * n3 + 255) / 256, 256, 0, stream>>>(Ws[L], Wd[L], Wl[L], K, fo, Wcat);
        dim3 g(gx, n3 / 64);
        gemm2_kernel<false><<<g, 256, 0, stream>>>(h, HTOT, Wcat, n3, nullptr, asdv, n3,
                                                   M, K, nullptr, nullptr, nullptr);
        if (fo == 64)
            attn_kernel<1><<<(N_NODES + 3) / 4, 256, 0, stream>>>(h, asdv, Wp[L], bp[L],
                                                                  rowp, edata, K);
        else
            attn_kernel<2><<<(N_NODES + 3) / 4, 256, 0, stream>>>(h, asdv, Wp[L], bp[L],
                                                                  rowp, edata, K);
    }
    gemm2_kernel<true><<<dim3(gx, 1), 256, 0, stream>>>(h, HTOT, Wm1, 64, bm1, nullptr, 0,
                                                        M, HTOT, Wm2, bm2, out);
}

// Round 4
// 716.252 us; speedup vs baseline: 2.3481x; 1.3719x over previous
//
#include <hip/hip_runtime.h>
#include <hip/hip_bf16.h>
#include <hip/hip_fp16.h>
#include <math.h>

#define N_NODES 50000
#define N_EDGES 800000
#define ET (N_EDGES + N_NODES)
#define HTOT 400

typedef __attribute__((ext_vector_type(4))) float f32x4;
typedef __attribute__((ext_vector_type(8))) short bf16x8;

static const int INS_h[4] = {16, 80, 144, 272};
static const int K32_h[4] = {32, 96, 160, 288};
static const int HO_h[4]  = {64, 64, 128, 128};

// ---------------- CSR build ----------------

__global__ void copy_x_kernel(const float* __restrict__ x, __hip_bfloat16* __restrict__ h) {
    int i = blockIdx.x * blockDim.x + threadIdx.x;
    if (i >= N_NODES * 16) return;
    int n = i >> 4, c = i & 15;
    h[n * HTOT + c] = __float2bfloat16(x[i]);
}

__global__ void hist_kernel(const int* __restrict__ ei, int* __restrict__ deg) {
    int e = blockIdx.x * blockDim.x + threadIdx.x;
    if (e >= ET) return;
    int dst = (e < N_EDGES) ? ei[N_EDGES + e] : (e - N_EDGES);
    atomicAdd(&deg[dst], 1);
}

__global__ __launch_bounds__(1024) void scan_kernel(const int* __restrict__ deg,
                                                    int* __restrict__ row_ptr,
                                                    int* __restrict__ cursor) {
    __shared__ int sums[1024];
    int t = threadIdx.x;
    const int CH = (N_NODES + 1023) / 1024;
    int beg = t * CH, end = min(beg + CH, N_NODES);
    int s = 0;
    for (int i = beg; i < end; ++i) s += deg[i];
    sums[t] = s;
    __syncthreads();
    for (int off = 1; off < 1024; off <<= 1) {
        int v2 = (t >= off) ? sums[t - off] : 0;
        __syncthreads();
        sums[t] += v2;
        __syncthreads();
    }
    int excl = (t == 0) ? 0 : sums[t - 1];
    for (int i = beg; i < end; ++i) {
        row_ptr[i] = excl;
        cursor[i] = excl;
        excl += deg[i];
    }
    if (t == 0) row_ptr[N_NODES] = sums[1023];
}

__global__ void scatter_kernel(const int* __restrict__ ei, const float* __restrict__ x,
                               int* __restrict__ cursor, float4* __restrict__ edata) {
    int e = blockIdx.x * blockDim.x + threadIdx.x;
    if (e >= ET) return;
    int src, dst;
    if (e < N_EDGES) { src = ei[e]; dst = ei[N_EDGES + e]; }
    else             { src = dst = e - N_EDGES; }
    int p = atomicAdd(&cursor[dst], 1);
    float dx = x[dst * 16 + 0] - x[src * 16 + 0];
    float dy = x[dst * 16 + 1] - x[src * 16 + 1];
    float dz = x[dst * 16 + 2] - x[src * 16 + 2];
    edata[p] = make_float4(__int_as_float(src), dx, dy, dz);
}

// ------- weight concat+transpose+pad: Wt[c][kk] (bf16), c in [0,nparts*fo), kk in [0,K32) -------

__global__ void concat_wT_kernel(const float* __restrict__ W0, const float* __restrict__ W1,
                                 const float* __restrict__ W2, int K, int K32, int fo,
                                 __hip_bfloat16* __restrict__ Wt, int total) {
    int i = blockIdx.x * blockDim.x + threadIdx.x;
    if (i >= total) return;
    int c = i / K32, kk = i - c * K32;
    float v = 0.f;
    if (kk < K) {
        const float* s; int cc;
        if (c < fo)          { s = W0; cc = c; }
        else if (c < 2 * fo) { s = W1; cc = c - fo; }
        else                 { s = W2; cc = c - 2 * fo; }
        v = s[kk * fo + cc];
    }
    Wt[i] = __float2bfloat16(v);
}

// ---------------- bf16 MFMA GEMM: C[M x N] = A[M x K] * W[K x N], fp32 accum ----------------
// A bf16 [M][lda], Wt bf16 [N][K32] (transposed, zero-padded). BM=128 BN=64 BK=32, 4 waves.
// C output fp16 (asdv). FUSE: N==64: epilogue out = (C+bias) @ W2 + b2 (64->8), fp32.

template <bool FUSE>
__global__ __launch_bounds__(256) void gemm3_kernel(
    const __hip_bfloat16* __restrict__ A, int lda,
    const __hip_bfloat16* __restrict__ Wt, int K32,
    const float* __restrict__ bias,
    __half* __restrict__ C, int ldc,
    int M, int K,
    const float* __restrict__ W2, const float* __restrict__ b2,
    float* __restrict__ out) {
    __shared__ float smemf[9728];                 // 38.9 KB, aliased below
    ushort* sA = (ushort*)smemf;                  // [2][128*40] bf16
    ushort* sB = (ushort*)smemf + 10240;          // [2][64*40]
    const int t = threadIdx.x;
    const int r0 = blockIdx.x * 128, c0 = blockIdx.y * 64;
    const int w = t >> 6, lane = t & 63;
    const int l15 = lane & 15, l4 = lane >> 4;

    f32x4 acc[2][4];
#pragma unroll
    for (int i = 0; i < 2; ++i)
#pragma unroll
        for (int j = 0; j < 4; ++j) acc[i][j] = (f32x4){0.f, 0.f, 0.f, 0.f};

    const int sr = t >> 2, sq = (t & 3) * 8;
    const int ar1 = min(r0 + sr, M - 1), ar2 = min(r0 + sr + 64, M - 1);
    const size_t a1b = (size_t)ar1 * lda, a2b = (size_t)ar2 * lda;
    const size_t wb = (size_t)(c0 + sr) * K32;
    const int nk = K32 >> 5;

    uint4 ga0, ga1, gb;
    const uint4 z4 = {0u, 0u, 0u, 0u};
    {
        const int kk = sq;
        const bool ok = kk < K;
        ga0 = ok ? *(const uint4*)(A + a1b + kk) : z4;
        ga1 = ok ? *(const uint4*)(A + a2b + kk) : z4;
        gb  = *(const uint4*)(Wt + wb + kk);
        *(uint4*)(sA + sr * 40 + sq) = ga0;
        *(uint4*)(sA + (sr + 64) * 40 + sq) = ga1;
        *(uint4*)(sB + sr * 40 + sq) = gb;
    }
    __syncthreads();

    int buf = 0;
    for (int kc = 0; kc < nk; ++kc) {
        const bool nx = (kc + 1) < nk;
        if (nx) {
            const int kk = (kc + 1) * 32 + sq;
            const bool ok = kk < K;
            ga0 = ok ? *(const uint4*)(A + a1b + kk) : z4;
            ga1 = ok ? *(const uint4*)(A + a2b + kk) : z4;
            gb  = *(const uint4*)(Wt + wb + kk);
        }
        const ushort* bA = sA + buf * 5120 + w * 1280;
        const ushort* bB = sB + buf * 2560;
        bf16x8 af[2], bfr[4];
#pragma unroll
        for (int i = 0; i < 2; ++i)
            af[i] = *(const bf16x8*)(bA + (i * 16 + l15) * 40 + l4 * 8);
#pragma unroll
        for (int j = 0; j < 4; ++j)
            bfr[j] = *(const bf16x8*)(bB + (j * 16 + l15) * 40 + l4 * 8);
#pragma unroll
        for (int i = 0; i < 2; ++i)
#pragma unroll
            for (int j = 0; j < 4; ++j)
                acc[i][j] = __builtin_amdgcn_mfma_f32_16x16x32_bf16(af[i], bfr[j], acc[i][j], 0, 0, 0);
        if (nx) {
            const int ob = buf ^ 1;
            *(uint4*)(sA + ob * 5120 + sr * 40 + sq) = ga0;
            *(uint4*)(sA + ob * 5120 + (sr + 64) * 40 + sq) = ga1;
            *(uint4*)(sB + ob * 2560 + sr * 40 + sq) = gb;
        }
        __syncthreads();
        buf ^= 1;
    }

    if (!FUSE) {
#pragma unroll
        for (int i = 0; i < 2; ++i)
#pragma unroll
            for (int j = 0; j < 4; ++j)
#pragma unroll
                for (int p = 0; p < 4; ++p) {
                    int row = r0 + w * 32 + i * 16 + l4 * 4 + p;
                    int col = c0 + j * 16 + l15;
                    if (row < M) C[(size_t)row * ldc + col] = __float2half(acc[i][j][p]);
                }
    } else {
#pragma unroll
        for (int i = 0; i < 2; ++i)
#pragma unroll
            for (int j = 0; j < 4; ++j)
#pragma unroll
                for (int p = 0; p < 4; ++p) {
                    int lrow = w * 32 + i * 16 + l4 * 4 + p;
                    int col = j * 16 + l15;
                    smemf[lrow * 68 + col] = acc[i][j][p] + bias[col];
                }
        smemf[8704 + t] = W2[t];
        smemf[8704 + 256 + t] = W2[256 + t];
        __syncthreads();
        const int row = t >> 1, oc = (t & 1) * 4;
        f32x4 o = *(const f32x4*)&b2[oc];
#pragma unroll 8
        for (int k = 0; k < 64; ++k) {
            float a = smemf[row * 68 + k];
            o += a * *(const f32x4*)&smemf[8704 + k * 8 + oc];
        }
        const int grow = r0 + row;
        if (grow < M) *(f32x4*)&out[(size_t)grow * 8 + oc] = o;
    }
}

// ---------------- attention: one wave per node, lanes cover channels (fp16 asdv) ----------------
// asdv layout: [n][3*FO] fp16: [0,FO)=a_src, [FO,2FO)=a_dst, [2FO,3FO)=v

template <int CPL>
__global__ __launch_bounds__(256) void attn_kernel(
    __hip_bfloat16* __restrict__ h,
    const __half* __restrict__ asdv,
    const float* __restrict__ Wp, const float* __restrict__ bp,
    const int* __restrict__ rowp, const float4* __restrict__ edata,
    int colbase) {
    constexpr int FO = 64 * CPL, LD = 3 * FO;
    int wid = (blockIdx.x * blockDim.x + threadIdx.x) >> 6;
    if (wid >= N_NODES) return;
    const int lane = threadIdx.x & 63;
    const int n = wid;
    const int cb = CPL * lane;
    float wp0[CPL], wp1[CPL], wp2[CPL], bpv[CPL], ad[CPL], m[CPL], s[CPL], num[CPL];
#pragma unroll
    for (int j = 0; j < CPL; ++j) {
        int c = cb + j;
        wp0[j] = Wp[c];
        wp1[j] = Wp[FO + c];
        wp2[j] = Wp[2 * FO + c];
        bpv[j] = bp[c];
        ad[j] = __half2float(asdv[(size_t)n * LD + FO + c]);
        m[j] = -INFINITY; s[j] = 0.f; num[j] = 0.f;
    }
    const int beg = rowp[n], end = rowp[n + 1];
    float4 ed = edata[beg];                  // degree >= 1 (self-loop)
    for (int i = beg; i < end; ++i) {
        float4 cur = ed;
        if (i + 1 < end) ed = edata[i + 1];
        const int src = __float_as_int(cur.x);
        float as[CPL], vv[CPL];
        if (CPL == 2) {
            const __half2* rs2 = (const __half2*)(asdv + (size_t)src * LD);
            __half2 a2 = rs2[lane];
            __half2 v2 = rs2[FO + lane];
            as[0] = __half2float(a2.x);
            as[CPL - 1] = __half2float(a2.y);
            vv[0] = __half2float(v2.x);
            vv[CPL - 1] = __half2float(v2.y);
        } else {
            const __half* rs = asdv + (size_t)src * LD;
            as[0] = __half2float(rs[cb]);
            vv[0] = __half2float(rs[2 * FO + cb]);
        }
#pragma unroll
        for (int j = 0; j < CPL; ++j) {
            float delta = fmaf(cur.y, wp0[j], fmaf(cur.z, wp1[j], fmaf(cur.w, wp2[j], bpv[j])));
            float alpha = ad[j] - as[j] + delta;
            float mn = fmaxf(m[j], alpha);
            float e0 = __expf(m[j] - mn);
            float p = __expf(alpha - mn);
            s[j] = s[j] * e0 + p;
            num[j] = num[j] * e0 + p * (vv[j] + delta);
            m[j] = mn;
        }
    }
#pragma unroll
    for (int j = 0; j < CPL; ++j) {
        float xi = num[j] / s[j];
        xi = xi > 0.f ? xi : 0.01f * xi;
        h[(size_t)n * HTOT + colbase + cb + j] = __float2bfloat16(xi);
    }
}

// ---------------- launch ----------------

extern "C" void kernel_launch(void* const* d_in, const int* in_sizes, int n_in,
                              void* d_out, int out_size, void* d_ws, size_t ws_size,
                              hipStream_t stream) {
    const float* x = (const float*)d_in[0];
    const int* ei = (const int*)d_in[1];
    const float *Wl[4], *Ws[4], *Wd[4], *Wp[4], *bp[4];
    for (int i = 0; i < 4; ++i) {
        Wl[i] = (const float*)d_in[2 + 5 * i];
        Ws[i] = (const float*)d_in[3 + 5 * i];
        Wd[i] = (const float*)d_in[4 + 5 * i];
        Wp[i] = (const float*)d_in[5 + 5 * i];
        bp[i] = (const float*)d_in[6 + 5 * i];
    }
    const float* Wm1 = (const float*)d_in[22];
    const float* bm1 = (const float*)d_in[23];
    const float* Wm2 = (const float*)d_in[24];
    const float* bm2 = (const float*)d_in[25];
    float* out = (float*)d_out;

    char* ws = (char*)d_ws;
    size_t off = 0;
    auto alloc = [&](size_t bytes) -> void* {
        void* p = ws + off;
        off += (bytes + 255) & ~(size_t)255;
        return p;
    };
    __hip_bfloat16* h = (__hip_bfloat16*)alloc((size_t)N_NODES * HTOT * 2);    // 40 MB
    __half* asdv = (__half*)alloc((size_t)N_NODES * 384 * 2);                  // 38.4 MB
    __hip_bfloat16* Wt = (__hip_bfloat16*)alloc((size_t)384 * 416 * 2);
    int* deg = (int*)alloc((size_t)N_NODES * 4);
    int* rowp = (int*)alloc((size_t)(N_NODES + 1) * 4);
    int* cursor = (int*)alloc((size_t)N_NODES * 4);
    float4* edata = (float4*)alloc((size_t)ET * 16);                           // 13.6 MB
    (void)ws_size; (void)n_in; (void)in_sizes; (void)out_size;

    hipMemsetAsync(deg, 0, (size_t)N_NODES * 4, stream);
    copy_x_kernel<<<(N_NODES * 16 + 255) / 256, 256, 0, stream>>>(x, h);
    hist_kernel<<<(ET + 255) / 256, 256, 0, stream>>>(ei, deg);
    scan_kernel<<<1, 1024, 0, stream>>>(deg, rowp, cursor);
    scatter_kernel<<<(ET + 255) / 256, 256, 0, stream>>>(ei, x, cursor, edata);

    const int M = N_NODES;
    const int gx = (M + 127) / 128;
    for (int L = 0; L < 4; ++L) {
        const int K = INS_h[L], K32 = K32_h[L], fo = HO_h[L], n3 = 3 * fo;
        const int total = n3 * K32;
        concat_wT_kernel<<<(total + 255) / 256, 256, 0, stream>>>(Ws[L], Wd[L], Wl[L],
                                                                  K, K32, fo, Wt, total);
        dim3 g(gx, n3 / 64);
        gemm3_kernel<false><<<g, 256, 0, stream>>>(h, HTOT, Wt, K32, nullptr, asdv, n3,
                                                   M, K, nullptr, nullptr, nullptr);
        if (fo == 64)
            attn_kernel<1><<<(N_NODES + 3) / 4, 256, 0, stream>>>(h, asdv, Wp[L], bp[L],
                                                                  rowp, edata, K);
        else
            attn_kernel<2><<<(N_NODES + 3) / 4, 256, 0, stream>>>(h, asdv, Wp[L], bp[L],
                                                                  rowp, edata, K);
    }
    {
        const int total = 64 * 416;
        concat_wT_kernel<<<(total + 255) / 256, 256, 0, stream>>>(Wm1, nullptr, nullptr,
                                                                  400, 416, 64, Wt, total);
        gemm3_kernel<true><<<dim3(gx, 1), 256, 0, stream>>>(h, HTOT, Wt, 416, bm1,
                                                            nullptr, 0, M, 400, Wm2, bm2, out);
    }
}

// Round 5
// 695.039 us; speedup vs baseline: 2.4197x; 1.0305x over previous
//
#include <hip/hip_runtime.h>
#include <hip/hip_bf16.h>
#include <hip/hip_fp16.h>
#include <math.h>

#define N_NODES 50000
#define N_EDGES 800000
#define ET (N_EDGES + N_NODES)
#define HTOT 400

typedef __attribute__((ext_vector_type(4))) float f32x4;
typedef __attribute__((ext_vector_type(8))) short bf16x8;

static const int INS_h[4] = {16, 80, 144, 272};
static const int K32_h[4] = {32, 96, 160, 288};
static const int HO_h[4]  = {64, 64, 128, 128};

// ---------------- CSR build ----------------

__global__ void copy_x_kernel(const float* __restrict__ x, __hip_bfloat16* __restrict__ h) {
    int i = blockIdx.x * blockDim.x + threadIdx.x;
    if (i >= N_NODES * 16) return;
    int n = i >> 4, c = i & 15;
    h[n * HTOT + c] = __float2bfloat16(x[i]);
}

__global__ void hist_kernel(const int* __restrict__ ei, int* __restrict__ deg) {
    int e = blockIdx.x * blockDim.x + threadIdx.x;
    if (e >= ET) return;
    int dst = (e < N_EDGES) ? ei[N_EDGES + e] : (e - N_EDGES);
    atomicAdd(&deg[dst], 1);
}

__global__ __launch_bounds__(1024) void scan_kernel(const int* __restrict__ deg,
                                                    int* __restrict__ row_ptr,
                                                    int* __restrict__ cursor) {
    __shared__ int sums[1024];
    int t = threadIdx.x;
    const int CH = (N_NODES + 1023) / 1024;
    int beg = t * CH, end = min(beg + CH, N_NODES);
    int s = 0;
    for (int i = beg; i < end; ++i) s += deg[i];
    sums[t] = s;
    __syncthreads();
    for (int off = 1; off < 1024; off <<= 1) {
        int v2 = (t >= off) ? sums[t - off] : 0;
        __syncthreads();
        sums[t] += v2;
        __syncthreads();
    }
    int excl = (t == 0) ? 0 : sums[t - 1];
    for (int i = beg; i < end; ++i) {
        row_ptr[i] = excl;
        cursor[i] = excl;
        excl += deg[i];
    }
    if (t == 0) row_ptr[N_NODES] = sums[1023];
}

__global__ void scatter_kernel(const int* __restrict__ ei, const float* __restrict__ x,
                               int* __restrict__ cursor, float4* __restrict__ edata) {
    int e = blockIdx.x * blockDim.x + threadIdx.x;
    if (e >= ET) return;
    int src, dst;
    if (e < N_EDGES) { src = ei[e]; dst = ei[N_EDGES + e]; }
    else             { src = dst = e - N_EDGES; }
    int p = atomicAdd(&cursor[dst], 1);
    float dx = x[dst * 16 + 0] - x[src * 16 + 0];
    float dy = x[dst * 16 + 1] - x[src * 16 + 1];
    float dz = x[dst * 16 + 2] - x[src * 16 + 2];
    edata[p] = make_float4(__int_as_float(src), dx, dy, dz);
}

// ------- weight concat+transpose+pad (bf16): parts [W0 | W1], c-major rows, K32 cols -------

__global__ void concat_wT_kernel(const float* __restrict__ W0, const float* __restrict__ W1,
                                 int K, int K32, int fo,
                                 __hip_bfloat16* __restrict__ Wt, int total) {
    int i = blockIdx.x * blockDim.x + threadIdx.x;
    if (i >= total) return;
    int c = i / K32, kk = i - c * K32;
    float v = 0.f;
    if (kk < K) {
        if (c < fo) v = W0[kk * fo + c];
        else        v = W1[kk * fo + (c - fo)];
    }
    Wt[i] = __float2bfloat16(v);
}

// ---------------- bf16 MFMA GEMM: C[M x N] = A[M x K] * W[K x N], fp32 accum ----------------
// A bf16 [M][lda], Wt bf16 [N][K32] (transposed, zero-padded). BM=128 BN=64 BK=32, 4 waves.
// !FUSE: N==2*fo, epilogue scatters fp16 into av[row][c][part] (part 0=a_src, 1=v).
// FUSE: N==64: epilogue out = (C+bias) @ W2 + b2 (64->8), fp32.

template <bool FUSE>
__global__ __launch_bounds__(256) void gemm3_kernel(
    const __hip_bfloat16* __restrict__ A, int lda,
    const __hip_bfloat16* __restrict__ Wt, int K32,
    const float* __restrict__ bias,
    __half* __restrict__ av, int fo,
    int M, int K,
    const float* __restrict__ W2, const float* __restrict__ b2,
    float* __restrict__ out) {
    __shared__ float smemf[9728];                 // 38.9 KB, aliased below
    ushort* sA = (ushort*)smemf;                  // [2][128*40] bf16
    ushort* sB = (ushort*)smemf + 10240;          // [2][64*40]
    const int t = threadIdx.x;
    const int r0 = blockIdx.x * 128, c0 = blockIdx.y * 64;
    const int w = t >> 6, lane = t & 63;
    const int l15 = lane & 15, l4 = lane >> 4;

    f32x4 acc[2][4];
#pragma unroll
    for (int i = 0; i < 2; ++i)
#pragma unroll
        for (int j = 0; j < 4; ++j) acc[i][j] = (f32x4){0.f, 0.f, 0.f, 0.f};

    const int sr = t >> 2, sq = (t & 3) * 8;
    const int ar1 = min(r0 + sr, M - 1), ar2 = min(r0 + sr + 64, M - 1);
    const size_t a1b = (size_t)ar1 * lda, a2b = (size_t)ar2 * lda;
    const size_t wb = (size_t)(c0 + sr) * K32;
    const int nk = K32 >> 5;

    uint4 ga0, ga1, gb;
    const uint4 z4 = {0u, 0u, 0u, 0u};
    {
        const int kk = sq;
        const bool ok = kk < K;
        ga0 = ok ? *(const uint4*)(A + a1b + kk) : z4;
        ga1 = ok ? *(const uint4*)(A + a2b + kk) : z4;
        gb  = *(const uint4*)(Wt + wb + kk);
        *(uint4*)(sA + sr * 40 + sq) = ga0;
        *(uint4*)(sA + (sr + 64) * 40 + sq) = ga1;
        *(uint4*)(sB + sr * 40 + sq) = gb;
    }
    __syncthreads();

    int buf = 0;
    for (int kc = 0; kc < nk; ++kc) {
        const bool nx = (kc + 1) < nk;
        if (nx) {
            const int kk = (kc + 1) * 32 + sq;
            const bool ok = kk < K;
            ga0 = ok ? *(const uint4*)(A + a1b + kk) : z4;
            ga1 = ok ? *(const uint4*)(A + a2b + kk) : z4;
            gb  = *(const uint4*)(Wt + wb + kk);
        }
        const ushort* bA = sA + buf * 5120 + w * 1280;
        const ushort* bB = sB + buf * 2560;
        bf16x8 af[2], bfr[4];
#pragma unroll
        for (int i = 0; i < 2; ++i)
            af[i] = *(const bf16x8*)(bA + (i * 16 + l15) * 40 + l4 * 8);
#pragma unroll
        for (int j = 0; j < 4; ++j)
            bfr[j] = *(const bf16x8*)(bB + (j * 16 + l15) * 40 + l4 * 8);
#pragma unroll
        for (int i = 0; i < 2; ++i)
#pragma unroll
            for (int j = 0; j < 4; ++j)
                acc[i][j] = __builtin_amdgcn_mfma_f32_16x16x32_bf16(af[i], bfr[j], acc[i][j], 0, 0, 0);
        if (nx) {
            const int ob = buf ^ 1;
            *(uint4*)(sA + ob * 5120 + sr * 40 + sq) = ga0;
            *(uint4*)(sA + ob * 5120 + (sr + 64) * 40 + sq) = ga1;
            *(uint4*)(sB + ob * 2560 + sr * 40 + sq) = gb;
        }
        __syncthreads();
        buf ^= 1;
    }

    if (!FUSE) {
#pragma unroll
        for (int i = 0; i < 2; ++i)
#pragma unroll
            for (int j = 0; j < 4; ++j)
#pragma unroll
                for (int p = 0; p < 4; ++p) {
                    int row = r0 + w * 32 + i * 16 + l4 * 4 + p;
                    int col = c0 + j * 16 + l15;          // in [0, 2*fo)
                    if (row < M) {
                        int part = col >= fo;
                        int cc = col - part * fo;
                        av[((size_t)row * fo + cc) * 2 + part] = __float2half(acc[i][j][p]);
                    }
                }
    } else {
#pragma unroll
        for (int i = 0; i < 2; ++i)
#pragma unroll
            for (int j = 0; j < 4; ++j)
#pragma unroll
                for (int p = 0; p < 4; ++p) {
                    int lrow = w * 32 + i * 16 + l4 * 4 + p;
                    int col = j * 16 + l15;
                    smemf[lrow * 68 + col] = acc[i][j][p] + bias[col];
                }
        smemf[8704 + t] = W2[t];
        smemf[8704 + 256 + t] = W2[256 + t];
        __syncthreads();
        const int row = t >> 1, oc = (t & 1) * 4;
        f32x4 o = *(const f32x4*)&b2[oc];
#pragma unroll 8
        for (int k = 0; k < 64; ++k) {
            float a = smemf[row * 68 + k];
            o += a * *(const f32x4*)&smemf[8704 + k * 8 + oc];
        }
        const int grow = r0 + row;
        if (grow < M) *(f32x4*)&out[(size_t)grow * 8 + oc] = o;
    }
}

// ---------------- attention: one wave per node, lanes cover channels ----------------
// av layout: [n][fo][2] fp16, [c][0]=a_src, [c][1]=v.  p = exp(delta - a_src), no max needed
// (a_dst cancels in the softmax; exponent args are O(1), far from fp32 exp limits).

template <int CPL>
__global__ __launch_bounds__(256) void attn_kernel(
    __hip_bfloat16* __restrict__ h,
    const __half* __restrict__ av,
    const float* __restrict__ Wp, const float* __restrict__ bp,
    const int* __restrict__ rowp, const float4* __restrict__ edata,
    int colbase) {
    constexpr int FO = 64 * CPL;
    int wid = (blockIdx.x * blockDim.x + threadIdx.x) >> 6;
    if (wid >= N_NODES) return;
    const int lane = threadIdx.x & 63;
    const int n = wid;
    const int cb = CPL * lane;
    float wp0[CPL], wp1[CPL], wp2[CPL], bpv[CPL], s[CPL], num[CPL];
#pragma unroll
    for (int j = 0; j < CPL; ++j) {
        int c = cb + j;
        wp0[j] = Wp[c];
        wp1[j] = Wp[FO + c];
        wp2[j] = Wp[2 * FO + c];
        bpv[j] = bp[c];
        s[j] = 0.f; num[j] = 0.f;
    }
    const int beg = rowp[n], end = rowp[n + 1];
    float4 ed = edata[beg];                  // degree >= 1 (self-loop)
    for (int i = beg; i < end; ++i) {
        float4 cur = ed;
        if (i + 1 < end) ed = edata[i + 1];
        const int src = __float_as_int(cur.x);
        float as[CPL], vv[CPL];
        if (CPL == 2) {
            const uint2* rs = (const uint2*)(av + (size_t)src * FO * 2);
            uint2 u = rs[lane];
            __half2 h0 = *(__half2*)&u.x;
            __half2 h1 = *(__half2*)&u.y;
            as[0] = __half2float(h0.x); vv[0] = __half2float(h0.y);
            as[CPL - 1] = __half2float(h1.x); vv[CPL - 1] = __half2float(h1.y);
        } else {
            const uint* rs = (const uint*)(av + (size_t)src * FO * 2);
            uint u = rs[lane];
            __half2 h0 = *(__half2*)&u;
            as[0] = __half2float(h0.x); vv[0] = __half2float(h0.y);
        }
#pragma unroll
        for (int j = 0; j < CPL; ++j) {
            float delta = fmaf(cur.y, wp0[j], fmaf(cur.z, wp1[j], fmaf(cur.w, wp2[j], bpv[j])));
            float p = __expf(delta - as[j]);
            s[j] += p;
            num[j] = fmaf(p, vv[j] + delta, num[j]);
        }
    }
#pragma unroll
    for (int j = 0; j < CPL; ++j) {
        float xi = num[j] / s[j];
        xi = xi > 0.f ? xi : 0.01f * xi;
        h[(size_t)n * HTOT + colbase + cb + j] = __float2bfloat16(xi);
    }
}

// ---------------- launch ----------------

extern "C" void kernel_launch(void* const* d_in, const int* in_sizes, int n_in,
                              void* d_out, int out_size, void* d_ws, size_t ws_size,
                              hipStream_t stream) {
    const float* x = (const float*)d_in[0];
    const int* ei = (const int*)d_in[1];
    const float *Wl[4], *Ws[4], *Wp[4], *bp[4];
    for (int i = 0; i < 4; ++i) {
        Wl[i] = (const float*)d_in[2 + 5 * i];
        Ws[i] = (const float*)d_in[3 + 5 * i];
        Wp[i] = (const float*)d_in[5 + 5 * i];
        bp[i] = (const float*)d_in[6 + 5 * i];
    }
    const float* Wm1 = (const float*)d_in[22];
    const float* bm1 = (const float*)d_in[23];
    const float* Wm2 = (const float*)d_in[24];
    const float* bm2 = (const float*)d_in[25];
    float* out = (float*)d_out;

    char* ws = (char*)d_ws;
    size_t off = 0;
    auto alloc = [&](size_t bytes) -> void* {
        void* p = ws + off;
        off += (bytes + 255) & ~(size_t)255;
        return p;
    };
    __hip_bfloat16* h = (__hip_bfloat16*)alloc((size_t)N_NODES * HTOT * 2);    // 40 MB
    __half* av = (__half*)alloc((size_t)N_NODES * 256 * 2);                    // 25.6 MB
    __hip_bfloat16* Wt = (__hip_bfloat16*)alloc((size_t)384 * 416 * 2);
    int* deg = (int*)alloc((size_t)N_NODES * 4);
    int* rowp = (int*)alloc((size_t)(N_NODES + 1) * 4);
    int* cursor = (int*)alloc((size_t)N_NODES * 4);
    float4* edata = (float4*)alloc((size_t)ET * 16);                           // 13.6 MB
    (void)ws_size; (void)n_in; (void)in_sizes; (void)out_size;

    hipMemsetAsync(deg, 0, (size_t)N_NODES * 4, stream);
    copy_x_kernel<<<(N_NODES * 16 + 255) / 256, 256, 0, stream>>>(x, h);
    hist_kernel<<<(ET + 255) / 256, 256, 0, stream>>>(ei, deg);
    scan_kernel<<<1, 1024, 0, stream>>>(deg, rowp, cursor);
    scatter_kernel<<<(ET + 255) / 256, 256, 0, stream>>>(ei, x, cursor, edata);

    const int M = N_NODES;
    const int gx = (M + 127) / 128;
    for (int L = 0; L < 4; ++L) {
        const int K = INS_h[L], K32 = K32_h[L], fo = HO_h[L], n2 = 2 * fo;
        const int total = n2 * K32;
        concat_wT_kernel<<<(total + 255) / 256, 256, 0, stream>>>(Ws[L], Wl[L],
                                                                  K, K32, fo, Wt, total);
        dim3 g(gx, n2 / 64);
        gemm3_kernel<false><<<g, 256, 0, stream>>>(h, HTOT, Wt, K32, nullptr, av, fo,
                                                   M, K, nullptr, nullptr, nullptr);
        if (fo == 64)
            attn_kernel<1><<<(N_NODES + 3) / 4, 256, 0, stream>>>(h, av, Wp[L], bp[L],
                                                                  rowp, edata, K);
        else
            attn_kernel<2><<<(N_NODES + 3) / 4, 256, 0, stream>>>(h, av, Wp[L], bp[L],
                                                                  rowp, edata, K);
    }
    {
        const int total = 64 * 416;
        concat_wT_kernel<<<(total + 255) / 256, 256, 0, stream>>>(Wm1, nullptr,
                                                                  400, 416, 64, Wt, total);
        gemm3_kernel<true><<<dim3(gx, 1), 256, 0, stream>>>(h, HTOT, Wt, 416, bm1,
                                                            nullptr, 0, M, 400, Wm2, bm2, out);
    }
}

// Round 6
// 594.820 us; speedup vs baseline: 2.8274x; 1.1685x over previous
//
#include <hip/hip_runtime.h>
#include <hip/hip_bf16.h>
#include <hip/hip_fp16.h>
#include <math.h>

#define N_NODES 50000
#define N_EDGES 800000
#define ET (N_EDGES + N_NODES)
#define HTOT 400

#define SCAN_CHUNK 1024
#define NSCB ((N_NODES + SCAN_CHUNK - 1) / SCAN_CHUNK)   // 49

typedef __attribute__((ext_vector_type(4))) float f32x4;
typedef __attribute__((ext_vector_type(8))) short bf16x8;

static const int INS_h[4] = {16, 80, 144, 272};
static const int K32_h[4] = {32, 96, 160, 288};
static const int HO_h[4]  = {64, 64, 128, 128};

// ---------------- CSR build ----------------

__global__ void copy_x_kernel(const float* __restrict__ x, __hip_bfloat16* __restrict__ h) {
    int i = blockIdx.x * blockDim.x + threadIdx.x;
    if (i >= N_NODES * 16) return;
    int n = i >> 4, c = i & 15;
    h[n * HTOT + c] = __float2bfloat16(x[i]);
}

__global__ void hist_kernel(const int* __restrict__ ei, int* __restrict__ deg) {
    int e = blockIdx.x * blockDim.x + threadIdx.x;
    if (e >= ET) return;
    int dst = (e < N_EDGES) ? ei[N_EDGES + e] : (e - N_EDGES);
    atomicAdd(&deg[dst], 1);
}

// 3-phase device-wide exclusive scan of deg[50000] -> row_ptr / cursor
__global__ __launch_bounds__(256) void scan_p1(const int* __restrict__ deg,
                                               int* __restrict__ bsum) {
    __shared__ int red[256];
    const int b = blockIdx.x, t = threadIdx.x;
    const int base = b * SCAN_CHUNK + t * 4;
    int s = 0;
#pragma unroll
    for (int j = 0; j < 4; ++j) {
        int i = base + j;
        if (i < N_NODES) s += deg[i];
    }
    red[t] = s;
    __syncthreads();
    for (int off = 128; off > 0; off >>= 1) {
        if (t < off) red[t] += red[t + off];
        __syncthreads();
    }
    if (t == 0) bsum[b] = red[0];
}

__global__ void scan_p2(int* __restrict__ bsum) {
    const int lane = threadIdx.x;            // blockDim = 64
    int v = (lane < NSCB) ? bsum[lane] : 0;
    int inc = v;
#pragma unroll
    for (int off = 1; off < 64; off <<= 1) {
        int u = __shfl_up(inc, off);
        if (lane >= off) inc += u;
    }
    if (lane < NSCB) bsum[lane] = inc - v;   // exclusive
    if (lane == 63) bsum[NSCB] = inc;        // grand total
}

__global__ __launch_bounds__(256) void scan_p3(const int* __restrict__ deg,
                                               const int* __restrict__ bsum,
                                               int* __restrict__ row_ptr,
                                               int* __restrict__ cursor) {
    __shared__ int ts[256];
    const int b = blockIdx.x, t = threadIdx.x;
    const int base = b * SCAN_CHUNK + t * 4;
    int v[4];
    int s = 0;
#pragma unroll
    for (int j = 0; j < 4; ++j) {
        int i = base + j;
        v[j] = (i < N_NODES) ? deg[i] : 0;
        s += v[j];
    }
    ts[t] = s;
    __syncthreads();
    for (int off = 1; off < 256; off <<= 1) {
        int u = (t >= off) ? ts[t - off] : 0;
        __syncthreads();
        ts[t] += u;
        __syncthreads();
    }
    int excl = bsum[b] + ts[t] - s;
#pragma unroll
    for (int j = 0; j < 4; ++j) {
        int i = base + j;
        if (i < N_NODES) {
            row_ptr[i] = excl;
            cursor[i] = excl;
            excl += v[j];
        }
    }
    if (b == 0 && t == 0) row_ptr[N_NODES] = bsum[NSCB];
}

__global__ void scatter_kernel(const int* __restrict__ ei, const float* __restrict__ x,
                               int* __restrict__ cursor, float4* __restrict__ edata) {
    int e = blockIdx.x * blockDim.x + threadIdx.x;
    if (e >= ET) return;
    int src, dst;
    if (e < N_EDGES) { src = ei[e]; dst = ei[N_EDGES + e]; }
    else             { src = dst = e - N_EDGES; }
    int p = atomicAdd(&cursor[dst], 1);
    float dx = x[dst * 16 + 0] - x[src * 16 + 0];
    float dy = x[dst * 16 + 1] - x[src * 16 + 1];
    float dz = x[dst * 16 + 2] - x[src * 16 + 2];
    edata[p] = make_float4(__int_as_float(src), dx, dy, dz);
}

// ------- weight concat+transpose+pad (bf16): parts [W0 | W1], c-major rows, K32 cols -------

__global__ void concat_wT_kernel(const float* __restrict__ W0, const float* __restrict__ W1,
                                 int K, int K32, int fo,
                                 __hip_bfloat16* __restrict__ Wt, int total) {
    int i = blockIdx.x * blockDim.x + threadIdx.x;
    if (i >= total) return;
    int c = i / K32, kk = i - c * K32;
    float v = 0.f;
    if (kk < K) {
        if (c < fo) v = W0[kk * fo + c];
        else        v = W1[kk * fo + (c - fo)];
    }
    Wt[i] = __float2bfloat16(v);
}

// ---------------- bf16 MFMA GEMM: C[M x N] = A[M x K] * W[K x N], fp32 accum ----------------
// A bf16 [M][lda], Wt bf16 [N][K32] (transposed, zero-padded). BM=128 BN=64 BK=32, 4 waves.
// !FUSE: N==2*fo, epilogue scatters fp16 into av[row][c][part] (part 0=a_src, 1=v).
// FUSE: N==64: epilogue out = (C+bias) @ W2 + b2 (64->8), fp32.

template <bool FUSE>
__global__ __launch_bounds__(256) void gemm3_kernel(
    const __hip_bfloat16* __restrict__ A, int lda,
    const __hip_bfloat16* __restrict__ Wt, int K32,
    const float* __restrict__ bias,
    __half* __restrict__ av, int fo,
    int M, int K,
    const float* __restrict__ W2, const float* __restrict__ b2,
    float* __restrict__ out) {
    __shared__ float smemf[9728];                 // 38.9 KB, aliased below
    ushort* sA = (ushort*)smemf;                  // [2][128*40] bf16
    ushort* sB = (ushort*)smemf + 10240;          // [2][64*40]
    const int t = threadIdx.x;
    const int r0 = blockIdx.x * 128, c0 = blockIdx.y * 64;
    const int w = t >> 6, lane = t & 63;
    const int l15 = lane & 15, l4 = lane >> 4;

    f32x4 acc[2][4];
#pragma unroll
    for (int i = 0; i < 2; ++i)
#pragma unroll
        for (int j = 0; j < 4; ++j) acc[i][j] = (f32x4){0.f, 0.f, 0.f, 0.f};

    const int sr = t >> 2, sq = (t & 3) * 8;
    const int ar1 = min(r0 + sr, M - 1), ar2 = min(r0 + sr + 64, M - 1);
    const size_t a1b = (size_t)ar1 * lda, a2b = (size_t)ar2 * lda;
    const size_t wb = (size_t)(c0 + sr) * K32;
    const int nk = K32 >> 5;

    uint4 ga0, ga1, gb;
    const uint4 z4 = {0u, 0u, 0u, 0u};
    {
        const int kk = sq;
        const bool ok = kk < K;
        ga0 = ok ? *(const uint4*)(A + a1b + kk) : z4;
        ga1 = ok ? *(const uint4*)(A + a2b + kk) : z4;
        gb  = *(const uint4*)(Wt + wb + kk);
        *(uint4*)(sA + sr * 40 + sq) = ga0;
        *(uint4*)(sA + (sr + 64) * 40 + sq) = ga1;
        *(uint4*)(sB + sr * 40 + sq) = gb;
    }
    __syncthreads();

    int buf = 0;
    for (int kc = 0; kc < nk; ++kc) {
        const bool nx = (kc + 1) < nk;
        if (nx) {
            const int kk = (kc + 1) * 32 + sq;
            const bool ok = kk < K;
            ga0 = ok ? *(const uint4*)(A + a1b + kk) : z4;
            ga1 = ok ? *(const uint4*)(A + a2b + kk) : z4;
            gb  = *(const uint4*)(Wt + wb + kk);
        }
        const ushort* bA = sA + buf * 5120 + w * 1280;
        const ushort* bB = sB + buf * 2560;
        bf16x8 af[2], bfr[4];
#pragma unroll
        for (int i = 0; i < 2; ++i)
            af[i] = *(const bf16x8*)(bA + (i * 16 + l15) * 40 + l4 * 8);
#pragma unroll
        for (int j = 0; j < 4; ++j)
            bfr[j] = *(const bf16x8*)(bB + (j * 16 + l15) * 40 + l4 * 8);
#pragma unroll
        for (int i = 0; i < 2; ++i)
#pragma unroll
            for (int j = 0; j < 4; ++j)
                acc[i][j] = __builtin_amdgcn_mfma_f32_16x16x32_bf16(af[i], bfr[j], acc[i][j], 0, 0, 0);
        if (nx) {
            const int ob = buf ^ 1;
            *(uint4*)(sA + ob * 5120 + sr * 40 + sq) = ga0;
            *(uint4*)(sA + ob * 5120 + (sr + 64) * 40 + sq) = ga1;
            *(uint4*)(sB + ob * 2560 + sr * 40 + sq) = gb;
        }
        __syncthreads();
        buf ^= 1;
    }

    if (!FUSE) {
#pragma unroll
        for (int i = 0; i < 2; ++i)
#pragma unroll
            for (int j = 0; j < 4; ++j)
#pragma unroll
                for (int p = 0; p < 4; ++p) {
                    int row = r0 + w * 32 + i * 16 + l4 * 4 + p;
                    int col = c0 + j * 16 + l15;          // in [0, 2*fo)
                    if (row < M) {
                        int part = col >= fo;
                        int cc = col - part * fo;
                        av[((size_t)row * fo + cc) * 2 + part] = __float2half(acc[i][j][p]);
                    }
                }
    } else {
#pragma unroll
        for (int i = 0; i < 2; ++i)
#pragma unroll
            for (int j = 0; j < 4; ++j)
#pragma unroll
                for (int p = 0; p < 4; ++p) {
                    int lrow = w * 32 + i * 16 + l4 * 4 + p;
                    int col = j * 16 + l15;
                    smemf[lrow * 68 + col] = acc[i][j][p] + bias[col];
                }
        smemf[8704 + t] = W2[t];
        smemf[8704 + 256 + t] = W2[256 + t];
        __syncthreads();
        const int row = t >> 1, oc = (t & 1) * 4;
        f32x4 o = *(const f32x4*)&b2[oc];
#pragma unroll 8
        for (int k = 0; k < 64; ++k) {
            float a = smemf[row * 68 + k];
            o += a * *(const f32x4*)&smemf[8704 + k * 8 + oc];
        }
        const int grow = r0 + row;
        if (grow < M) *(f32x4*)&out[(size_t)grow * 8 + oc] = o;
    }
}

// ---------------- attention: one wave per node, lanes cover channels ----------------
// av layout: [n][fo][2] fp16, [c][0]=a_src, [c][1]=v.  p = exp(delta - a_src), no max needed
// (a_dst cancels in the softmax; exponent args are O(1), far from fp32 exp limits).

template <int CPL>
__global__ __launch_bounds__(256) void attn_kernel(
    __hip_bfloat16* __restrict__ h,
    const __half* __restrict__ av,
    const float* __restrict__ Wp, const float* __restrict__ bp,
    const int* __restrict__ rowp, const float4* __restrict__ edata,
    int colbase) {
    constexpr int FO = 64 * CPL;
    int wid = (blockIdx.x * blockDim.x + threadIdx.x) >> 6;
    if (wid >= N_NODES) return;
    const int lane = threadIdx.x & 63;
    const int n = wid;
    const int cb = CPL * lane;
    float wp0[CPL], wp1[CPL], wp2[CPL], bpv[CPL], s[CPL], num[CPL];
#pragma unroll
    for (int j = 0; j < CPL; ++j) {
        int c = cb + j;
        wp0[j] = Wp[c];
        wp1[j] = Wp[FO + c];
        wp2[j] = Wp[2 * FO + c];
        bpv[j] = bp[c];
        s[j] = 0.f; num[j] = 0.f;
    }
    const int beg = rowp[n], end = rowp[n + 1];
    float4 ed = edata[beg];                  // degree >= 1 (self-loop)
    for (int i = beg; i < end; ++i) {
        float4 cur = ed;
        if (i + 1 < end) ed = edata[i + 1];
        const int src = __float_as_int(cur.x);
        float as[CPL], vv[CPL];
        if (CPL == 2) {
            const uint2* rs = (const uint2*)(av + (size_t)src * FO * 2);
            uint2 u = rs[lane];
            __half2 h0 = *(__half2*)&u.x;
            __half2 h1 = *(__half2*)&u.y;
            as[0] = __half2float(h0.x); vv[0] = __half2float(h0.y);
            as[CPL - 1] = __half2float(h1.x); vv[CPL - 1] = __half2float(h1.y);
        } else {
            const uint* rs = (const uint*)(av + (size_t)src * FO * 2);
            uint u = rs[lane];
            __half2 h0 = *(__half2*)&u;
            as[0] = __half2float(h0.x); vv[0] = __half2float(h0.y);
        }
#pragma unroll
        for (int j = 0; j < CPL; ++j) {
            float delta = fmaf(cur.y, wp0[j], fmaf(cur.z, wp1[j], fmaf(cur.w, wp2[j], bpv[j])));
            float p = __expf(delta - as[j]);
            s[j] += p;
            num[j] = fmaf(p, vv[j] + delta, num[j]);
        }
    }
#pragma unroll
    for (int j = 0; j < CPL; ++j) {
        float xi = num[j] / s[j];
        xi = xi > 0.f ? xi : 0.01f * xi;
        h[(size_t)n * HTOT + colbase + cb + j] = __float2bfloat16(xi);
    }
}

// ---------------- launch ----------------

extern "C" void kernel_launch(void* const* d_in, const int* in_sizes, int n_in,
                              void* d_out, int out_size, void* d_ws, size_t ws_size,
                              hipStream_t stream) {
    const float* x = (const float*)d_in[0];
    const int* ei = (const int*)d_in[1];
    const float *Wl[4], *Ws[4], *Wp[4], *bp[4];
    for (int i = 0; i < 4; ++i) {
        Wl[i] = (const float*)d_in[2 + 5 * i];
        Ws[i] = (const float*)d_in[3 + 5 * i];
        Wp[i] = (const float*)d_in[5 + 5 * i];
        bp[i] = (const float*)d_in[6 + 5 * i];
    }
    const float* Wm1 = (const float*)d_in[22];
    const float* bm1 = (const float*)d_in[23];
    const float* Wm2 = (const float*)d_in[24];
    const float* bm2 = (const float*)d_in[25];
    float* out = (float*)d_out;

    char* ws = (char*)d_ws;
    size_t off = 0;
    auto alloc = [&](size_t bytes) -> void* {
        void* p = ws + off;
        off += (bytes + 255) & ~(size_t)255;
        return p;
    };
    __hip_bfloat16* h = (__hip_bfloat16*)alloc((size_t)N_NODES * HTOT * 2);    // 40 MB
    __half* av = (__half*)alloc((size_t)N_NODES * 256 * 2);                    // 25.6 MB
    __hip_bfloat16* Wt = (__hip_bfloat16*)alloc((size_t)384 * 416 * 2);
    int* deg = (int*)alloc((size_t)N_NODES * 4);
    int* rowp = (int*)alloc((size_t)(N_NODES + 1) * 4);
    int* cursor = (int*)alloc((size_t)N_NODES * 4);
    int* bsum = (int*)alloc((size_t)(NSCB + 1) * 4);
    float4* edata = (float4*)alloc((size_t)ET * 16);                           // 13.6 MB
    (void)ws_size; (void)n_in; (void)in_sizes; (void)out_size;

    hipMemsetAsync(deg, 0, (size_t)N_NODES * 4, stream);
    copy_x_kernel<<<(N_NODES * 16 + 255) / 256, 256, 0, stream>>>(x, h);
    hist_kernel<<<(ET + 255) / 256, 256, 0, stream>>>(ei, deg);
    scan_p1<<<NSCB, 256, 0, stream>>>(deg, bsum);
    scan_p2<<<1, 64, 0, stream>>>(bsum);
    scan_p3<<<NSCB, 256, 0, stream>>>(deg, bsum, rowp, cursor);
    scatter_kernel<<<(ET + 255) / 256, 256, 0, stream>>>(ei, x, cursor, edata);

    const int M = N_NODES;
    const int gx = (M + 127) / 128;
    for (int L = 0; L < 4; ++L) {
        const int K = INS_h[L], K32 = K32_h[L], fo = HO_h[L], n2 = 2 * fo;
        const int total = n2 * K32;
        concat_wT_kernel<<<(total + 255) / 256, 256, 0, stream>>>(Ws[L], Wl[L],
                                                                  K, K32, fo, Wt, total);
        dim3 g(gx, n2 / 64);
        gemm3_kernel<false><<<g, 256, 0, stream>>>(h, HTOT, Wt, K32, nullptr, av, fo,
                                                   M, K, nullptr, nullptr, nullptr);
        if (fo == 64)
            attn_kernel<1><<<(N_NODES + 3) / 4, 256, 0, stream>>>(h, av, Wp[L], bp[L],
                                                                  rowp, edata, K);
        else
            attn_kernel<2><<<(N_NODES + 3) / 4, 256, 0, stream>>>(h, av, Wp[L], bp[L],
                                                                  rowp, edata, K);
    }
    {
        const int total = 64 * 416;
        concat_wT_kernel<<<(total + 255) / 256, 256, 0, stream>>>(Wm1, nullptr,
                                                                  400, 416, 64, Wt, total);
        gemm3_kernel<true><<<dim3(gx, 1), 256, 0, stream>>>(h, HTOT, Wt, 416, bm1,
                                                            nullptr, 0, M, 400, Wm2, bm2, out);
    }
}

// Round 7
// 567.637 us; speedup vs baseline: 2.9628x; 1.0479x over previous
//
#include <hip/hip_runtime.h>
#include <hip/hip_bf16.h>
#include <hip/hip_fp16.h>
#include <math.h>

#define N_NODES 50000
#define N_EDGES 800000
#define ET (N_EDGES + N_NODES)
#define HTOT 400

#define SCAN_CHUNK 1024
#define NSCB ((N_NODES + SCAN_CHUNK - 1) / SCAN_CHUNK)   // 49

typedef __attribute__((ext_vector_type(4))) float f32x4;
typedef __attribute__((ext_vector_type(8))) short bf16x8;

static const int INS_h[4] = {16, 80, 144, 272};
static const int K32_h[4] = {32, 96, 160, 288};
static const int HO_h[4]  = {64, 64, 128, 128};

// ---------------- CSR build ----------------

__global__ void copy_x_kernel(const float* __restrict__ x, __hip_bfloat16* __restrict__ h) {
    int i = blockIdx.x * blockDim.x + threadIdx.x;
    if (i >= N_NODES * 16) return;
    int n = i >> 4, c = i & 15;
    h[n * HTOT + c] = __float2bfloat16(x[i]);
}

__global__ void hist_kernel(const int* __restrict__ ei, int* __restrict__ deg) {
    int e = blockIdx.x * blockDim.x + threadIdx.x;
    if (e >= ET) return;
    int dst = (e < N_EDGES) ? ei[N_EDGES + e] : (e - N_EDGES);
    atomicAdd(&deg[dst], 1);
}

// 3-phase device-wide exclusive scan of deg[50000] -> row_ptr / cursor
__global__ __launch_bounds__(256) void scan_p1(const int* __restrict__ deg,
                                               int* __restrict__ bsum) {
    __shared__ int red[256];
    const int b = blockIdx.x, t = threadIdx.x;
    const int base = b * SCAN_CHUNK + t * 4;
    int s = 0;
#pragma unroll
    for (int j = 0; j < 4; ++j) {
        int i = base + j;
        if (i < N_NODES) s += deg[i];
    }
    red[t] = s;
    __syncthreads();
    for (int off = 128; off > 0; off >>= 1) {
        if (t < off) red[t] += red[t + off];
        __syncthreads();
    }
    if (t == 0) bsum[b] = red[0];
}

__global__ void scan_p2(int* __restrict__ bsum) {
    const int lane = threadIdx.x;            // blockDim = 64
    int v = (lane < NSCB) ? bsum[lane] : 0;
    int inc = v;
#pragma unroll
    for (int off = 1; off < 64; off <<= 1) {
        int u = __shfl_up(inc, off);
        if (lane >= off) inc += u;
    }
    if (lane < NSCB) bsum[lane] = inc - v;   // exclusive
    if (lane == 63) bsum[NSCB] = inc;        // grand total
}

__global__ __launch_bounds__(256) void scan_p3(const int* __restrict__ deg,
                                               const int* __restrict__ bsum,
                                               int* __restrict__ row_ptr,
                                               int* __restrict__ cursor) {
    __shared__ int ts[256];
    const int b = blockIdx.x, t = threadIdx.x;
    const int base = b * SCAN_CHUNK + t * 4;
    int v[4];
    int s = 0;
#pragma unroll
    for (int j = 0; j < 4; ++j) {
        int i = base + j;
        v[j] = (i < N_NODES) ? deg[i] : 0;
        s += v[j];
    }
    ts[t] = s;
    __syncthreads();
    for (int off = 1; off < 256; off <<= 1) {
        int u = (t >= off) ? ts[t - off] : 0;
        __syncthreads();
        ts[t] += u;
        __syncthreads();
    }
    int excl = bsum[b] + ts[t] - s;
#pragma unroll
    for (int j = 0; j < 4; ++j) {
        int i = base + j;
        if (i < N_NODES) {
            row_ptr[i] = excl;
            cursor[i] = excl;
            excl += v[j];
        }
    }
    if (b == 0 && t == 0) row_ptr[N_NODES] = bsum[NSCB];
}

__global__ void scatter_kernel(const int* __restrict__ ei, const float* __restrict__ x,
                               int* __restrict__ cursor, float4* __restrict__ edata) {
    int e = blockIdx.x * blockDim.x + threadIdx.x;
    if (e >= ET) return;
    int src, dst;
    if (e < N_EDGES) { src = ei[e]; dst = ei[N_EDGES + e]; }
    else             { src = dst = e - N_EDGES; }
    int p = atomicAdd(&cursor[dst], 1);
    float dx = x[dst * 16 + 0] - x[src * 16 + 0];
    float dy = x[dst * 16 + 1] - x[src * 16 + 1];
    float dz = x[dst * 16 + 2] - x[src * 16 + 2];
    edata[p] = make_float4(__int_as_float(src), dx, dy, dz);
}

// ------- weight concat+transpose+pad (bf16): parts [W0 | W1], c-major rows, K32 cols -------

__global__ void concat_wT_kernel(const float* __restrict__ W0, const float* __restrict__ W1,
                                 int K, int K32, int fo,
                                 __hip_bfloat16* __restrict__ Wt, int total) {
    int i = blockIdx.x * blockDim.x + threadIdx.x;
    if (i >= total) return;
    int c = i / K32, kk = i - c * K32;
    float v = 0.f;
    if (kk < K) {
        if (c < fo) v = W0[kk * fo + c];
        else        v = W1[kk * fo + (c - fo)];
    }
    Wt[i] = __float2bfloat16(v);
}

// ---------------- bf16 MFMA GEMM: C[M x N] = A[M x K] * W[K x N], fp32 accum ----------------
// A bf16 [M][lda], Wt bf16 [N][K32] (transposed, zero-padded). BM=128 BN=64 BK=32, 4 waves.
// !FUSE: N==2*fo, epilogue scatters fp16 into av[row][c][part] (part 0=a_src, 1=v).
// FUSE: N==64: epilogue out = (C+bias) @ W2 + b2 (64->8), fp32.

template <bool FUSE>
__global__ __launch_bounds__(256) void gemm3_kernel(
    const __hip_bfloat16* __restrict__ A, int lda,
    const __hip_bfloat16* __restrict__ Wt, int K32,
    const float* __restrict__ bias,
    __half* __restrict__ av, int fo,
    int M, int K,
    const float* __restrict__ W2, const float* __restrict__ b2,
    float* __restrict__ out) {
    __shared__ float smemf[9728];                 // 38.9 KB, aliased below
    ushort* sA = (ushort*)smemf;                  // [2][128*40] bf16
    ushort* sB = (ushort*)smemf + 10240;          // [2][64*40]
    const int t = threadIdx.x;
    const int r0 = blockIdx.x * 128, c0 = blockIdx.y * 64;
    const int w = t >> 6, lane = t & 63;
    const int l15 = lane & 15, l4 = lane >> 4;

    f32x4 acc[2][4];
#pragma unroll
    for (int i = 0; i < 2; ++i)
#pragma unroll
        for (int j = 0; j < 4; ++j) acc[i][j] = (f32x4){0.f, 0.f, 0.f, 0.f};

    const int sr = t >> 2, sq = (t & 3) * 8;
    const int ar1 = min(r0 + sr, M - 1), ar2 = min(r0 + sr + 64, M - 1);
    const size_t a1b = (size_t)ar1 * lda, a2b = (size_t)ar2 * lda;
    const size_t wb = (size_t)(c0 + sr) * K32;
    const int nk = K32 >> 5;

    uint4 ga0, ga1, gb;
    const uint4 z4 = {0u, 0u, 0u, 0u};
    {
        const int kk = sq;
        const bool ok = kk < K;
        ga0 = ok ? *(const uint4*)(A + a1b + kk) : z4;
        ga1 = ok ? *(const uint4*)(A + a2b + kk) : z4;
        gb  = *(const uint4*)(Wt + wb + kk);
        *(uint4*)(sA + sr * 40 + sq) = ga0;
        *(uint4*)(sA + (sr + 64) * 40 + sq) = ga1;
        *(uint4*)(sB + sr * 40 + sq) = gb;
    }
    __syncthreads();

    int buf = 0;
    for (int kc = 0; kc < nk; ++kc) {
        const bool nx = (kc + 1) < nk;
        if (nx) {
            const int kk = (kc + 1) * 32 + sq;
            const bool ok = kk < K;
            ga0 = ok ? *(const uint4*)(A + a1b + kk) : z4;
            ga1 = ok ? *(const uint4*)(A + a2b + kk) : z4;
            gb  = *(const uint4*)(Wt + wb + kk);
        }
        const ushort* bA = sA + buf * 5120 + w * 1280;
        const ushort* bB = sB + buf * 2560;
        bf16x8 af[2], bfr[4];
#pragma unroll
        for (int i = 0; i < 2; ++i)
            af[i] = *(const bf16x8*)(bA + (i * 16 + l15) * 40 + l4 * 8);
#pragma unroll
        for (int j = 0; j < 4; ++j)
            bfr[j] = *(const bf16x8*)(bB + (j * 16 + l15) * 40 + l4 * 8);
#pragma unroll
        for (int i = 0; i < 2; ++i)
#pragma unroll
            for (int j = 0; j < 4; ++j)
                acc[i][j] = __builtin_amdgcn_mfma_f32_16x16x32_bf16(af[i], bfr[j], acc[i][j], 0, 0, 0);
        if (nx) {
            const int ob = buf ^ 1;
            *(uint4*)(sA + ob * 5120 + sr * 40 + sq) = ga0;
            *(uint4*)(sA + ob * 5120 + (sr + 64) * 40 + sq) = ga1;
            *(uint4*)(sB + ob * 2560 + sr * 40 + sq) = gb;
        }
        __syncthreads();
        buf ^= 1;
    }

    if (!FUSE) {
#pragma unroll
        for (int i = 0; i < 2; ++i)
#pragma unroll
            for (int j = 0; j < 4; ++j)
#pragma unroll
                for (int p = 0; p < 4; ++p) {
                    int row = r0 + w * 32 + i * 16 + l4 * 4 + p;
                    int col = c0 + j * 16 + l15;          // in [0, 2*fo)
                    if (row < M) {
                        int part = col >= fo;
                        int cc = col - part * fo;
                        av[((size_t)row * fo + cc) * 2 + part] = __float2half(acc[i][j][p]);
                    }
                }
    } else {
#pragma unroll
        for (int i = 0; i < 2; ++i)
#pragma unroll
            for (int j = 0; j < 4; ++j)
#pragma unroll
                for (int p = 0; p < 4; ++p) {
                    int lrow = w * 32 + i * 16 + l4 * 4 + p;
                    int col = j * 16 + l15;
                    smemf[lrow * 68 + col] = acc[i][j][p] + bias[col];
                }
        smemf[8704 + t] = W2[t];
        smemf[8704 + 256 + t] = W2[256 + t];
        __syncthreads();
        const int row = t >> 1, oc = (t & 1) * 4;
        f32x4 o = *(const f32x4*)&b2[oc];
#pragma unroll 8
        for (int k = 0; k < 64; ++k) {
            float a = smemf[row * 68 + k];
            o += a * *(const f32x4*)&smemf[8704 + k * 8 + oc];
        }
        const int grow = r0 + row;
        if (grow < M) *(f32x4*)&out[(size_t)grow * 8 + oc] = o;
    }
}

// ---------------- attention: one wave per node, lanes cover channels ----------------
// av layout: [n][fo][2] fp16, [c][0]=a_src, [c][1]=v.  p = exp(delta - a_src), no max needed
// (a_dst cancels in the softmax; exponent args are O(1), far from fp32 exp limits).
// Edge loop is software-pipelined: av-gather for edge i+1 and edata-load for i+2 issue
// before the compute of edge i (2 loads in flight per wave).

template <int CPL>
__global__ __launch_bounds__(256) void attn_kernel(
    __hip_bfloat16* __restrict__ h,
    const __half* __restrict__ av,
    const float* __restrict__ Wp, const float* __restrict__ bp,
    const int* __restrict__ rowp, const float4* __restrict__ edata,
    int colbase) {
    constexpr int FO = 64 * CPL;
    int wid = (blockIdx.x * blockDim.x + threadIdx.x) >> 6;
    if (wid >= N_NODES) return;
    const int lane = threadIdx.x & 63;
    const int n = wid;
    const int cb = CPL * lane;
    float wp0[CPL], wp1[CPL], wp2[CPL], bpv[CPL], s[CPL], num[CPL];
#pragma unroll
    for (int j = 0; j < CPL; ++j) {
        int c = cb + j;
        wp0[j] = Wp[c];
        wp1[j] = Wp[FO + c];
        wp2[j] = Wp[2 * FO + c];
        bpv[j] = bp[c];
        s[j] = 0.f; num[j] = 0.f;
    }
    const int beg = rowp[n], end = rowp[n + 1];
    const int last = end - 1;                // degree >= 1 (self-loop)

    uint u_cur[CPL], u_nxt[CPL];
    auto load_av = [&](int src, uint* u) {
        if (CPL == 2) {
            uint2 q = *(const uint2*)((const uint*)(av + (size_t)src * FO * 2) + 2 * lane);
            u[0] = q.x; u[CPL - 1] = q.y;
        } else {
            u[0] = *((const uint*)(av + (size_t)src * FO * 2) + lane);
        }
    };
    auto compute = [&](const float4& cur, const uint* u) {
#pragma unroll
        for (int j = 0; j < CPL; ++j) {
            __half2 hv = *(__half2*)&u[j];
            float as = __half2float(hv.x);
            float vv = __half2float(hv.y);
            float delta = fmaf(cur.y, wp0[j], fmaf(cur.z, wp1[j], fmaf(cur.w, wp2[j], bpv[j])));
            float p = __expf(delta - as);
            s[j] += p;
            num[j] = fmaf(p, vv + delta, num[j]);
        }
    };

    float4 ed_cur = edata[beg];
    float4 ed_nxt = edata[min(beg + 1, last)];
    load_av(__float_as_int(ed_cur.x), u_cur);
    for (int i = beg; i < last; ++i) {
        load_av(__float_as_int(ed_nxt.x), u_nxt);
        float4 ed_n2 = edata[min(i + 2, last)];
        compute(ed_cur, u_cur);
        ed_cur = ed_nxt; ed_nxt = ed_n2;
#pragma unroll
        for (int j = 0; j < CPL; ++j) u_cur[j] = u_nxt[j];
    }
    compute(ed_cur, u_cur);

#pragma unroll
    for (int j = 0; j < CPL; ++j) {
        float xi = num[j] / s[j];
        xi = xi > 0.f ? xi : 0.01f * xi;
        h[(size_t)n * HTOT + colbase + cb + j] = __float2bfloat16(xi);
    }
}

// ---------------- launch ----------------

extern "C" void kernel_launch(void* const* d_in, const int* in_sizes, int n_in,
                              void* d_out, int out_size, void* d_ws, size_t ws_size,
                              hipStream_t stream) {
    const float* x = (const float*)d_in[0];
    const int* ei = (const int*)d_in[1];
    const float *Wl[4], *Ws[4], *Wp[4], *bp[4];
    for (int i = 0; i < 4; ++i) {
        Wl[i] = (const float*)d_in[2 + 5 * i];
        Ws[i] = (const float*)d_in[3 + 5 * i];
        Wp[i] = (const float*)d_in[5 + 5 * i];
        bp[i] = (const float*)d_in[6 + 5 * i];
    }
    const float* Wm1 = (const float*)d_in[22];
    const float* bm1 = (const float*)d_in[23];
    const float* Wm2 = (const float*)d_in[24];
    const float* bm2 = (const float*)d_in[25];
    float* out = (float*)d_out;

    char* ws = (char*)d_ws;
    size_t off = 0;
    auto alloc = [&](size_t bytes) -> void* {
        void* p = ws + off;
        off += (bytes + 255) & ~(size_t)255;
        return p;
    };
    __hip_bfloat16* h = (__hip_bfloat16*)alloc((size_t)N_NODES * HTOT * 2);    // 40 MB
    __half* av = (__half*)alloc((size_t)N_NODES * 256 * 2);                    // 25.6 MB
    __hip_bfloat16* Wt = (__hip_bfloat16*)alloc((size_t)384 * 416 * 2);
    int* deg = (int*)alloc((size_t)N_NODES * 4);
    int* rowp = (int*)alloc((size_t)(N_NODES + 1) * 4);
    int* cursor = (int*)alloc((size_t)N_NODES * 4);
    int* bsum = (int*)alloc((size_t)(NSCB + 1) * 4);
    float4* edata = (float4*)alloc((size_t)ET * 16);                           // 13.6 MB
    (void)ws_size; (void)n_in; (void)in_sizes; (void)out_size;

    hipMemsetAsync(deg, 0, (size_t)N_NODES * 4, stream);
    copy_x_kernel<<<(N_NODES * 16 + 255) / 256, 256, 0, stream>>>(x, h);
    hist_kernel<<<(ET + 255) / 256, 256, 0, stream>>>(ei, deg);
    scan_p1<<<NSCB, 256, 0, stream>>>(deg, bsum);
    scan_p2<<<1, 64, 0, stream>>>(bsum);
    scan_p3<<<NSCB, 256, 0, stream>>>(deg, bsum, rowp, cursor);
    scatter_kernel<<<(ET + 255) / 256, 256, 0, stream>>>(ei, x, cursor, edata);

    const int M = N_NODES;
    const int gx = (M + 127) / 128;
    for (int L = 0; L < 4; ++L) {
        const int K = INS_h[L], K32 = K32_h[L], fo = HO_h[L], n2 = 2 * fo;
        const int total = n2 * K32;
        concat_wT_kernel<<<(total + 255) / 256, 256, 0, stream>>>(Ws[L], Wl[L],
                                                                  K, K32, fo, Wt, total);
        dim3 g(gx, n2 / 64);
        gemm3_kernel<false><<<g, 256, 0, stream>>>(h, HTOT, Wt, K32, nullptr, av, fo,
                                                   M, K, nullptr, nullptr, nullptr);
        if (fo == 64)
            attn_kernel<1><<<(N_NODES + 3) / 4, 256, 0, stream>>>(h, av, Wp[L], bp[L],
                                                                  rowp, edata, K);
        else
            attn_kernel<2><<<(N_NODES + 3) / 4, 256, 0, stream>>>(h, av, Wp[L], bp[L],
                                                                  rowp, edata, K);
    }
    {
        const int total = 64 * 416;
        concat_wT_kernel<<<(total + 255) / 256, 256, 0, stream>>>(Wm1, nullptr,
                                                                  400, 416, 64, Wt, total);
        gemm3_kernel<true><<<dim3(gx, 1), 256, 0, stream>>>(h, HTOT, Wt, 416, bm1,
                                                            nullptr, 0, M, 400, Wm2, bm2, out);
    }
}

// Round 8
// 538.869 us; speedup vs baseline: 3.1210x; 1.0534x over previous
//
#include <hip/hip_runtime.h>
#include <hip/hip_bf16.h>
#include <hip/hip_fp16.h>
#include <math.h>

#define N_NODES 50000
#define N_EDGES 800000
#define ET (N_EDGES + N_NODES)
#define HTOT 400

#define SCAN_CHUNK 1024
#define NSCB ((N_NODES + SCAN_CHUNK - 1) / SCAN_CHUNK)   // 49

// av is stored as per-64-channel half-buffers: half h occupies
// av + h*SH_HALF, layout [node][64][2] fp16 (256 B per node-row).
#define SH_HALF ((size_t)N_NODES * 128)    // in __half units
#define SH32    ((size_t)N_NODES * 64)     // in uint units

typedef __attribute__((ext_vector_type(4))) float f32x4;
typedef __attribute__((ext_vector_type(8))) short bf16x8;

static const int INS_h[4] = {16, 80, 144, 272};
static const int K32_h[4] = {32, 96, 160, 288};
static const int HO_h[4]  = {64, 64, 128, 128};

// ---------------- CSR build ----------------

__global__ void copy_x_kernel(const float* __restrict__ x, __hip_bfloat16* __restrict__ h) {
    int i = blockIdx.x * blockDim.x + threadIdx.x;
    if (i >= N_NODES * 16) return;
    int n = i >> 4, c = i & 15;
    h[n * HTOT + c] = __float2bfloat16(x[i]);
}

__global__ void hist_kernel(const int* __restrict__ ei, int* __restrict__ deg) {
    int e = blockIdx.x * blockDim.x + threadIdx.x;
    if (e >= ET) return;
    int dst = (e < N_EDGES) ? ei[N_EDGES + e] : (e - N_EDGES);
    atomicAdd(&deg[dst], 1);
}

// 3-phase device-wide exclusive scan of deg[50000] -> row_ptr / cursor
__global__ __launch_bounds__(256) void scan_p1(const int* __restrict__ deg,
                                               int* __restrict__ bsum) {
    __shared__ int red[256];
    const int b = blockIdx.x, t = threadIdx.x;
    const int base = b * SCAN_CHUNK + t * 4;
    int s = 0;
#pragma unroll
    for (int j = 0; j < 4; ++j) {
        int i = base + j;
        if (i < N_NODES) s += deg[i];
    }
    red[t] = s;
    __syncthreads();
    for (int off = 128; off > 0; off >>= 1) {
        if (t < off) red[t] += red[t + off];
        __syncthreads();
    }
    if (t == 0) bsum[b] = red[0];
}

__global__ void scan_p2(int* __restrict__ bsum) {
    const int lane = threadIdx.x;            // blockDim = 64
    int v = (lane < NSCB) ? bsum[lane] : 0;
    int inc = v;
#pragma unroll
    for (int off = 1; off < 64; off <<= 1) {
        int u = __shfl_up(inc, off);
        if (lane >= off) inc += u;
    }
    if (lane < NSCB) bsum[lane] = inc - v;   // exclusive
    if (lane == 63) bsum[NSCB] = inc;        // grand total
}

__global__ __launch_bounds__(256) void scan_p3(const int* __restrict__ deg,
                                               const int* __restrict__ bsum,
                                               int* __restrict__ row_ptr,
                                               int* __restrict__ cursor) {
    __shared__ int ts[256];
    const int b = blockIdx.x, t = threadIdx.x;
    const int base = b * SCAN_CHUNK + t * 4;
    int v[4];
    int s = 0;
#pragma unroll
    for (int j = 0; j < 4; ++j) {
        int i = base + j;
        v[j] = (i < N_NODES) ? deg[i] : 0;
        s += v[j];
    }
    ts[t] = s;
    __syncthreads();
    for (int off = 1; off < 256; off <<= 1) {
        int u = (t >= off) ? ts[t - off] : 0;
        __syncthreads();
        ts[t] += u;
        __syncthreads();
    }
    int excl = bsum[b] + ts[t] - s;
#pragma unroll
    for (int j = 0; j < 4; ++j) {
        int i = base + j;
        if (i < N_NODES) {
            row_ptr[i] = excl;
            cursor[i] = excl;
            excl += v[j];
        }
    }
    if (b == 0 && t == 0) row_ptr[N_NODES] = bsum[NSCB];
}

__global__ void scatter_kernel(const int* __restrict__ ei, const float* __restrict__ x,
                               int* __restrict__ cursor, float4* __restrict__ edata) {
    int e = blockIdx.x * blockDim.x + threadIdx.x;
    if (e >= ET) return;
    int src, dst;
    if (e < N_EDGES) { src = ei[e]; dst = ei[N_EDGES + e]; }
    else             { src = dst = e - N_EDGES; }
    int p = atomicAdd(&cursor[dst], 1);
    float dx = x[dst * 16 + 0] - x[src * 16 + 0];
    float dy = x[dst * 16 + 1] - x[src * 16 + 1];
    float dz = x[dst * 16 + 2] - x[src * 16 + 2];
    edata[p] = make_float4(__int_as_float(src), dx, dy, dz);
}

// ------- weight concat+transpose+pad (bf16): parts [W0 | W1], c-major rows, K32 cols -------

__global__ void concat_wT_kernel(const float* __restrict__ W0, const float* __restrict__ W1,
                                 int K, int K32, int fo,
                                 __hip_bfloat16* __restrict__ Wt, int total) {
    int i = blockIdx.x * blockDim.x + threadIdx.x;
    if (i >= total) return;
    int c = i / K32, kk = i - c * K32;
    float v = 0.f;
    if (kk < K) {
        if (c < fo) v = W0[kk * fo + c];
        else        v = W1[kk * fo + (c - fo)];
    }
    Wt[i] = __float2bfloat16(v);
}

// ---------------- bf16 MFMA GEMM: C[M x N] = A[M x K] * W[K x N], fp32 accum ----------------
// A bf16 [M][lda], Wt bf16 [N][K32] (transposed, zero-padded). BM=128 BN=64 BK=32, 4 waves.
// !FUSE: N==2*fo, epilogue scatters fp16 into av half-buffers:
//   col -> part = col>=fo, cc = col - part*fo; idx = (cc>>6)*SH_HALF + (row*64 + (cc&63))*2 + part
// FUSE: N==64: epilogue out = (C+bias) @ W2 + b2 (64->8), fp32.

template <bool FUSE>
__global__ __launch_bounds__(256) void gemm3_kernel(
    const __hip_bfloat16* __restrict__ A, int lda,
    const __hip_bfloat16* __restrict__ Wt, int K32,
    const float* __restrict__ bias,
    __half* __restrict__ av, int fo,
    int M, int K,
    const float* __restrict__ W2, const float* __restrict__ b2,
    float* __restrict__ out) {
    __shared__ float smemf[9728];                 // 38.9 KB, aliased below
    ushort* sA = (ushort*)smemf;                  // [2][128*40] bf16
    ushort* sB = (ushort*)smemf + 10240;          // [2][64*40]
    const int t = threadIdx.x;
    const int r0 = blockIdx.x * 128, c0 = blockIdx.y * 64;
    const int w = t >> 6, lane = t & 63;
    const int l15 = lane & 15, l4 = lane >> 4;

    f32x4 acc[2][4];
#pragma unroll
    for (int i = 0; i < 2; ++i)
#pragma unroll
        for (int j = 0; j < 4; ++j) acc[i][j] = (f32x4){0.f, 0.f, 0.f, 0.f};

    const int sr = t >> 2, sq = (t & 3) * 8;
    const int ar1 = min(r0 + sr, M - 1), ar2 = min(r0 + sr + 64, M - 1);
    const size_t a1b = (size_t)ar1 * lda, a2b = (size_t)ar2 * lda;
    const size_t wb = (size_t)(c0 + sr) * K32;
    const int nk = K32 >> 5;

    uint4 ga0, ga1, gb;
    const uint4 z4 = {0u, 0u, 0u, 0u};
    {
        const int kk = sq;
        const bool ok = kk < K;
        ga0 = ok ? *(const uint4*)(A + a1b + kk) : z4;
        ga1 = ok ? *(const uint4*)(A + a2b + kk) : z4;
        gb  = *(const uint4*)(Wt + wb + kk);
        *(uint4*)(sA + sr * 40 + sq) = ga0;
        *(uint4*)(sA + (sr + 64) * 40 + sq) = ga1;
        *(uint4*)(sB + sr * 40 + sq) = gb;
    }
    __syncthreads();

    int buf = 0;
    for (int kc = 0; kc < nk; ++kc) {
        const bool nx = (kc + 1) < nk;
        if (nx) {
            const int kk = (kc + 1) * 32 + sq;
            const bool ok = kk < K;
            ga0 = ok ? *(const uint4*)(A + a1b + kk) : z4;
            ga1 = ok ? *(const uint4*)(A + a2b + kk) : z4;
            gb  = *(const uint4*)(Wt + wb + kk);
        }
        const ushort* bA = sA + buf * 5120 + w * 1280;
        const ushort* bB = sB + buf * 2560;
        bf16x8 af[2], bfr[4];
#pragma unroll
        for (int i = 0; i < 2; ++i)
            af[i] = *(const bf16x8*)(bA + (i * 16 + l15) * 40 + l4 * 8);
#pragma unroll
        for (int j = 0; j < 4; ++j)
            bfr[j] = *(const bf16x8*)(bB + (j * 16 + l15) * 40 + l4 * 8);
#pragma unroll
        for (int i = 0; i < 2; ++i)
#pragma unroll
            for (int j = 0; j < 4; ++j)
                acc[i][j] = __builtin_amdgcn_mfma_f32_16x16x32_bf16(af[i], bfr[j], acc[i][j], 0, 0, 0);
        if (nx) {
            const int ob = buf ^ 1;
            *(uint4*)(sA + ob * 5120 + sr * 40 + sq) = ga0;
            *(uint4*)(sA + ob * 5120 + (sr + 64) * 40 + sq) = ga1;
            *(uint4*)(sB + ob * 2560 + sr * 40 + sq) = gb;
        }
        __syncthreads();
        buf ^= 1;
    }

    if (!FUSE) {
#pragma unroll
        for (int i = 0; i < 2; ++i)
#pragma unroll
            for (int j = 0; j < 4; ++j)
#pragma unroll
                for (int p = 0; p < 4; ++p) {
                    int row = r0 + w * 32 + i * 16 + l4 * 4 + p;
                    int col = c0 + j * 16 + l15;          // in [0, 2*fo)
                    if (row < M) {
                        int part = col >= fo;
                        int cc = col - part * fo;
                        size_t idx = (size_t)(cc >> 6) * SH_HALF
                                   + ((size_t)row * 64 + (cc & 63)) * 2 + part;
                        av[idx] = __float2half(acc[i][j][p]);
                    }
                }
    } else {
#pragma unroll
        for (int i = 0; i < 2; ++i)
#pragma unroll
            for (int j = 0; j < 4; ++j)
#pragma unroll
                for (int p = 0; p < 4; ++p) {
                    int lrow = w * 32 + i * 16 + l4 * 4 + p;
                    int col = j * 16 + l15;
                    smemf[lrow * 68 + col] = acc[i][j][p] + bias[col];
                }
        smemf[8704 + t] = W2[t];
        smemf[8704 + 256 + t] = W2[256 + t];
        __syncthreads();
        const int row = t >> 1, oc = (t & 1) * 4;
        f32x4 o = *(const f32x4*)&b2[oc];
#pragma unroll 8
        for (int k = 0; k < 64; ++k) {
            float a = smemf[row * 68 + k];
            o += a * *(const f32x4*)&smemf[8704 + k * 8 + oc];
        }
        const int grow = r0 + row;
        if (grow < M) *(f32x4*)&out[(size_t)grow * 8 + oc] = o;
    }
}

// ---------------- attention: one wave per node per 64-channel half ----------------
// Per-channel softmax -> channel halves are independent. half = blockIdx.x & (NH-1),
// so with round-robin block->XCD dispatch, each XCD touches only one 12.8 MB half-buffer.
// p = exp(delta - a_src): a_dst cancels in softmax; exponent args O(1), fp32-safe.
// Edge loop 2-deep software-pipelined.

template <int NHS>   // fo = 64 << NHS, halves NH = 1 << NHS
__global__ __launch_bounds__(256) void attn_kernel(
    __hip_bfloat16* __restrict__ h,
    const __half* __restrict__ av,
    const float* __restrict__ Wp, const float* __restrict__ bp,
    const int* __restrict__ rowp, const float4* __restrict__ edata,
    int colbase) {
    constexpr int FO = 64 << NHS;
    const int half = blockIdx.x & ((1 << NHS) - 1);
    const int nb = blockIdx.x >> NHS;
    const int wid = (nb * (int)blockDim.x + (int)threadIdx.x) >> 6;
    if (wid >= N_NODES) return;
    const int lane = threadIdx.x & 63;
    const int n = wid;
    const int c = half * 64 + lane;

    const float wp0 = Wp[c];
    const float wp1 = Wp[FO + c];
    const float wp2 = Wp[2 * FO + c];
    const float bpv = bp[c];
    float s = 0.f, num = 0.f;

    const uint* rowbase = (const uint*)av + (size_t)half * SH32;
    const int beg = rowp[n], end = rowp[n + 1];
    const int last = end - 1;                // degree >= 1 (self-loop)

    auto compute = [&](const float4& cur, uint u) {
        __half2 hv = *(__half2*)&u;
        float as = __half2float(hv.x);
        float vv = __half2float(hv.y);
        float delta = fmaf(cur.y, wp0, fmaf(cur.z, wp1, fmaf(cur.w, wp2, bpv)));
        float p = __expf(delta - as);
        s += p;
        num = fmaf(p, vv + delta, num);
    };

    float4 ed_cur = edata[beg];
    float4 ed_nxt = edata[min(beg + 1, last)];
    uint u_cur = rowbase[(size_t)__float_as_int(ed_cur.x) * 64 + lane];
    for (int i = beg; i < last; ++i) {
        uint u_nxt = rowbase[(size_t)__float_as_int(ed_nxt.x) * 64 + lane];
        float4 ed_n2 = edata[min(i + 2, last)];
        compute(ed_cur, u_cur);
        ed_cur = ed_nxt; ed_nxt = ed_n2;
        u_cur = u_nxt;
    }
    compute(ed_cur, u_cur);

    float xi = num / s;
    xi = xi > 0.f ? xi : 0.01f * xi;
    h[(size_t)n * HTOT + colbase + c] = __float2bfloat16(xi);
}

// ---------------- launch ----------------

extern "C" void kernel_launch(void* const* d_in, const int* in_sizes, int n_in,
                              void* d_out, int out_size, void* d_ws, size_t ws_size,
                              hipStream_t stream) {
    const float* x = (const float*)d_in[0];
    const int* ei = (const int*)d_in[1];
    const float *Wl[4], *Ws[4], *Wp[4], *bp[4];
    for (int i = 0; i < 4; ++i) {
        Wl[i] = (const float*)d_in[2 + 5 * i];
        Ws[i] = (const float*)d_in[3 + 5 * i];
        Wp[i] = (const float*)d_in[5 + 5 * i];
        bp[i] = (const float*)d_in[6 + 5 * i];
    }
    const float* Wm1 = (const float*)d_in[22];
    const float* bm1 = (const float*)d_in[23];
    const float* Wm2 = (const float*)d_in[24];
    const float* bm2 = (const float*)d_in[25];
    float* out = (float*)d_out;

    char* ws = (char*)d_ws;
    size_t off = 0;
    auto alloc = [&](size_t bytes) -> void* {
        void* p = ws + off;
        off += (bytes + 255) & ~(size_t)255;
        return p;
    };
    __hip_bfloat16* h = (__hip_bfloat16*)alloc((size_t)N_NODES * HTOT * 2);    // 40 MB
    __half* av = (__half*)alloc((size_t)N_NODES * 256 * 2);                    // 25.6 MB (2 half-buffers)
    __hip_bfloat16* Wt = (__hip_bfloat16*)alloc((size_t)384 * 416 * 2);
    int* deg = (int*)alloc((size_t)N_NODES * 4);
    int* rowp = (int*)alloc((size_t)(N_NODES + 1) * 4);
    int* cursor = (int*)alloc((size_t)N_NODES * 4);
    int* bsum = (int*)alloc((size_t)(NSCB + 1) * 4);
    float4* edata = (float4*)alloc((size_t)ET * 16);                           // 13.6 MB
    (void)ws_size; (void)n_in; (void)in_sizes; (void)out_size;

    hipMemsetAsync(deg, 0, (size_t)N_NODES * 4, stream);
    copy_x_kernel<<<(N_NODES * 16 + 255) / 256, 256, 0, stream>>>(x, h);
    hist_kernel<<<(ET + 255) / 256, 256, 0, stream>>>(ei, deg);
    scan_p1<<<NSCB, 256, 0, stream>>>(deg, bsum);
    scan_p2<<<1, 64, 0, stream>>>(bsum);
    scan_p3<<<NSCB, 256, 0, stream>>>(deg, bsum, rowp, cursor);
    scatter_kernel<<<(ET + 255) / 256, 256, 0, stream>>>(ei, x, cursor, edata);

    const int M = N_NODES;
    const int gx = (M + 127) / 128;
    const int nbn = (N_NODES + 3) / 4;       // node-blocks (4 waves/block)
    for (int L = 0; L < 4; ++L) {
        const int K = INS_h[L], K32 = K32_h[L], fo = HO_h[L], n2 = 2 * fo;
        const int total = n2 * K32;
        concat_wT_kernel<<<(total + 255) / 256, 256, 0, stream>>>(Ws[L], Wl[L],
                                                                  K, K32, fo, Wt, total);
        dim3 g(gx, n2 / 64);
        gemm3_kernel<false><<<g, 256, 0, stream>>>(h, HTOT, Wt, K32, nullptr, av, fo,
                                                   M, K, nullptr, nullptr, nullptr);
        if (fo == 64)
            attn_kernel<0><<<nbn, 256, 0, stream>>>(h, av, Wp[L], bp[L], rowp, edata, K);
        else
            attn_kernel<1><<<nbn * 2, 256, 0, stream>>>(h, av, Wp[L], bp[L], rowp, edata, K);
    }
    {
        const int total = 64 * 416;
        concat_wT_kernel<<<(total + 255) / 256, 256, 0, stream>>>(Wm1, nullptr,
                                                                  400, 416, 64, Wt, total);
        gemm3_kernel<true><<<dim3(gx, 1), 256, 0, stream>>>(h, HTOT, Wt, 416, bm1,
                                                            nullptr, 0, M, 400, Wm2, bm2, out);
    }
}

// Round 9
// 401.697 us; speedup vs baseline: 4.1868x; 1.3415x over previous
//
#include <hip/hip_runtime.h>
#include <hip/hip_bf16.h>
#include <hip/hip_fp16.h>
#include <math.h>

#define N_NODES 50000
#define N_EDGES 800000
#define ET (N_EDGES + N_NODES)
#define HTOT 400

#define SCAN_CHUNK 1024
#define NSCB ((N_NODES + SCAN_CHUNK - 1) / SCAN_CHUNK)   // 49

typedef __attribute__((ext_vector_type(4))) float f32x4;
typedef __attribute__((ext_vector_type(8))) short bf16x8;

static const int INS_h[4] = {16, 80, 144, 272};
static const int K32_h[4] = {32, 96, 160, 288};
static const int HO_h[4]  = {64, 64, 128, 128};

// ---------------- CSR build ----------------

__global__ void copy_x_kernel(const float* __restrict__ x, __hip_bfloat16* __restrict__ h) {
    int i = blockIdx.x * blockDim.x + threadIdx.x;
    if (i >= N_NODES * 16) return;
    int n = i >> 4, c = i & 15;
    h[n * HTOT + c] = __float2bfloat16(x[i]);
}

__global__ void hist_kernel(const int* __restrict__ ei, int* __restrict__ deg) {
    int e = blockIdx.x * blockDim.x + threadIdx.x;
    if (e >= ET) return;
    int dst = (e < N_EDGES) ? ei[N_EDGES + e] : (e - N_EDGES);
    atomicAdd(&deg[dst], 1);
}

// 3-phase device-wide exclusive scan of deg[50000] -> row_ptr / cursor
__global__ __launch_bounds__(256) void scan_p1(const int* __restrict__ deg,
                                               int* __restrict__ bsum) {
    __shared__ int red[256];
    const int b = blockIdx.x, t = threadIdx.x;
    const int base = b * SCAN_CHUNK + t * 4;
    int s = 0;
#pragma unroll
    for (int j = 0; j < 4; ++j) {
        int i = base + j;
        if (i < N_NODES) s += deg[i];
    }
    red[t] = s;
    __syncthreads();
    for (int off = 128; off > 0; off >>= 1) {
        if (t < off) red[t] += red[t + off];
        __syncthreads();
    }
    if (t == 0) bsum[b] = red[0];
}

__global__ void scan_p2(int* __restrict__ bsum) {
    const int lane = threadIdx.x;            // blockDim = 64
    int v = (lane < NSCB) ? bsum[lane] : 0;
    int inc = v;
#pragma unroll
    for (int off = 1; off < 64; off <<= 1) {
        int u = __shfl_up(inc, off);
        if (lane >= off) inc += u;
    }
    if (lane < NSCB) bsum[lane] = inc - v;   // exclusive
    if (lane == 63) bsum[NSCB] = inc;        // grand total
}

__global__ __launch_bounds__(256) void scan_p3(const int* __restrict__ deg,
                                               const int* __restrict__ bsum,
                                               int* __restrict__ row_ptr,
                                               int* __restrict__ cursor) {
    __shared__ int ts[256];
    const int b = blockIdx.x, t = threadIdx.x;
    const int base = b * SCAN_CHUNK + t * 4;
    int v[4];
    int s = 0;
#pragma unroll
    for (int j = 0; j < 4; ++j) {
        int i = base + j;
        v[j] = (i < N_NODES) ? deg[i] : 0;
        s += v[j];
    }
    ts[t] = s;
    __syncthreads();
    for (int off = 1; off < 256; off <<= 1) {
        int u = (t >= off) ? ts[t - off] : 0;
        __syncthreads();
        ts[t] += u;
        __syncthreads();
    }
    int excl = bsum[b] + ts[t] - s;
#pragma unroll
    for (int j = 0; j < 4; ++j) {
        int i = base + j;
        if (i < N_NODES) {
            row_ptr[i] = excl;
            cursor[i] = excl;
            excl += v[j];
        }
    }
    if (b == 0 && t == 0) row_ptr[N_NODES] = bsum[NSCB];
}

__global__ void scatter_kernel(const int* __restrict__ ei, const float* __restrict__ x,
                               int* __restrict__ cursor, float4* __restrict__ edata) {
    int e = blockIdx.x * blockDim.x + threadIdx.x;
    if (e >= ET) return;
    int src, dst;
    if (e < N_EDGES) { src = ei[e]; dst = ei[N_EDGES + e]; }
    else             { src = dst = e - N_EDGES; }
    int p = atomicAdd(&cursor[dst], 1);
    float dx = x[dst * 16 + 0] - x[src * 16 + 0];
    float dy = x[dst * 16 + 1] - x[src * 16 + 1];
    float dz = x[dst * 16 + 2] - x[src * 16 + 2];
    edata[p] = make_float4(__int_as_float(src), dx, dy, dz);
}

// ------- weight concat+transpose+pad (bf16): parts [W0 | W1], c-major rows, K32 cols -------

__global__ void concat_wT_kernel(const float* __restrict__ W0, const float* __restrict__ W1,
                                 int K, int K32, int fo,
                                 __hip_bfloat16* __restrict__ Wt, int total) {
    int i = blockIdx.x * blockDim.x + threadIdx.x;
    if (i >= total) return;
    int c = i / K32, kk = i - c * K32;
    float v = 0.f;
    if (kk < K) {
        if (c < fo) v = W0[kk * fo + c];
        else        v = W1[kk * fo + (c - fo)];
    }
    Wt[i] = __float2bfloat16(v);
}

// ---------------- bf16 MFMA GEMM: C[M x N] = A[M x K] * W[K x N], fp32 accum ----------------
// A bf16 [M][lda], Wt bf16 [N][K32] (transposed, zero-padded). BM=128 BN=64 BK=32, 4 waves.
// !FUSE: N==2*fo, epilogue scatters fp16 into av[row][cc][part] (part 0=a_src, 1=v).
// FUSE: N==64: epilogue out = (C+bias) @ W2 + b2 (64->8), fp32.

template <bool FUSE>
__global__ __launch_bounds__(256) void gemm3_kernel(
    const __hip_bfloat16* __restrict__ A, int lda,
    const __hip_bfloat16* __restrict__ Wt, int K32,
    const float* __restrict__ bias,
    __half* __restrict__ av, int fo,
    int M, int K,
    const float* __restrict__ W2, const float* __restrict__ b2,
    float* __restrict__ out) {
    __shared__ float smemf[9728];                 // 38.9 KB, aliased below
    ushort* sA = (ushort*)smemf;                  // [2][128*40] bf16
    ushort* sB = (ushort*)smemf + 10240;          // [2][64*40]
    const int t = threadIdx.x;
    const int r0 = blockIdx.x * 128, c0 = blockIdx.y * 64;
    const int w = t >> 6, lane = t & 63;
    const int l15 = lane & 15, l4 = lane >> 4;

    f32x4 acc[2][4];
#pragma unroll
    for (int i = 0; i < 2; ++i)
#pragma unroll
        for (int j = 0; j < 4; ++j) acc[i][j] = (f32x4){0.f, 0.f, 0.f, 0.f};

    const int sr = t >> 2, sq = (t & 3) * 8;
    const int ar1 = min(r0 + sr, M - 1), ar2 = min(r0 + sr + 64, M - 1);
    const size_t a1b = (size_t)ar1 * lda, a2b = (size_t)ar2 * lda;
    const size_t wb = (size_t)(c0 + sr) * K32;
    const int nk = K32 >> 5;

    uint4 ga0, ga1, gb;
    const uint4 z4 = {0u, 0u, 0u, 0u};
    {
        const int kk = sq;
        const bool ok = kk < K;
        ga0 = ok ? *(const uint4*)(A + a1b + kk) : z4;
        ga1 = ok ? *(const uint4*)(A + a2b + kk) : z4;
        gb  = *(const uint4*)(Wt + wb + kk);
        *(uint4*)(sA + sr * 40 + sq) = ga0;
        *(uint4*)(sA + (sr + 64) * 40 + sq) = ga1;
        *(uint4*)(sB + sr * 40 + sq) = gb;
    }
    __syncthreads();

    int buf = 0;
    for (int kc = 0; kc < nk; ++kc) {
        const bool nx = (kc + 1) < nk;
        if (nx) {
            const int kk = (kc + 1) * 32 + sq;
            const bool ok = kk < K;
            ga0 = ok ? *(const uint4*)(A + a1b + kk) : z4;
            ga1 = ok ? *(const uint4*)(A + a2b + kk) : z4;
            gb  = *(const uint4*)(Wt + wb + kk);
        }
        const ushort* bA = sA + buf * 5120 + w * 1280;
        const ushort* bB = sB + buf * 2560;
        bf16x8 af[2], bfr[4];
#pragma unroll
        for (int i = 0; i < 2; ++i)
            af[i] = *(const bf16x8*)(bA + (i * 16 + l15) * 40 + l4 * 8);
#pragma unroll
        for (int j = 0; j < 4; ++j)
            bfr[j] = *(const bf16x8*)(bB + (j * 16 + l15) * 40 + l4 * 8);
#pragma unroll
        for (int i = 0; i < 2; ++i)
#pragma unroll
            for (int j = 0; j < 4; ++j)
                acc[i][j] = __builtin_amdgcn_mfma_f32_16x16x32_bf16(af[i], bfr[j], acc[i][j], 0, 0, 0);
        if (nx) {
            const int ob = buf ^ 1;
            *(uint4*)(sA + ob * 5120 + sr * 40 + sq) = ga0;
            *(uint4*)(sA + ob * 5120 + (sr + 64) * 40 + sq) = ga1;
            *(uint4*)(sB + ob * 2560 + sr * 40 + sq) = gb;
        }
        __syncthreads();
        buf ^= 1;
    }

    if (!FUSE) {
#pragma unroll
        for (int i = 0; i < 2; ++i)
#pragma unroll
            for (int j = 0; j < 4; ++j)
#pragma unroll
                for (int p = 0; p < 4; ++p) {
                    int row = r0 + w * 32 + i * 16 + l4 * 4 + p;
                    int col = c0 + j * 16 + l15;          // in [0, 2*fo)
                    if (row < M) {
                        int part = col >= fo;
                        int cc = col - part * fo;
                        av[((size_t)row * fo + cc) * 2 + part] = __float2half(acc[i][j][p]);
                    }
                }
    } else {
#pragma unroll
        for (int i = 0; i < 2; ++i)
#pragma unroll
            for (int j = 0; j < 4; ++j)
#pragma unroll
                for (int p = 0; p < 4; ++p) {
                    int lrow = w * 32 + i * 16 + l4 * 4 + p;
                    int col = j * 16 + l15;
                    smemf[lrow * 68 + col] = acc[i][j][p] + bias[col];
                }
        smemf[8704 + t] = W2[t];
        smemf[8704 + 256 + t] = W2[256 + t];
        __syncthreads();
        const int row = t >> 1, oc = (t & 1) * 4;
        f32x4 o = *(const f32x4*)&b2[oc];
#pragma unroll 8
        for (int k = 0; k < 64; ++k) {
            float a = smemf[row * 68 + k];
            o += a * *(const f32x4*)&smemf[8704 + k * 8 + oc];
        }
        const int grow = r0 + row;
        if (grow < M) *(f32x4*)&out[(size_t)grow * 8 + oc] = o;
    }
}

// ---------------- attention: one wave per node; 4 edge slots x 16 lanes ----------------
// av layout: [n][fo][2] fp16, (a_src, v) pairs. p = exp(delta - a_src): a_dst cancels in
// the per-dst softmax; exponent args are O(1), fp32-safe.
// Lane = e*16 + l16: edge slot e (4 per iteration), l16 covers CPL=fo/16 channels via
// uint4 gathers. Cross-slot reduction: shfl_xor(16), shfl_xor(32) once per node.

template <int CPL>   // 4 (fo=64) or 8 (fo=128)
__global__ __launch_bounds__(256) void attn_kernel(
    __hip_bfloat16* __restrict__ h,
    const __half* __restrict__ av,
    const float* __restrict__ Wp, const float* __restrict__ bp,
    const int* __restrict__ rowp, const float4* __restrict__ edata,
    int colbase) {
    constexpr int FO = 16 * CPL;
    constexpr int NV = CPL / 4;            // uint4 gathers per lane
    const int wid = (blockIdx.x * (int)blockDim.x + (int)threadIdx.x) >> 6;
    if (wid >= N_NODES) return;
    const int lane = threadIdx.x & 63;
    const int e = lane >> 4, l16 = lane & 15;
    const int n = wid;
    const int cb = l16 * CPL;

    float wp0[CPL], wp1[CPL], wp2[CPL], bpv[CPL], s[CPL], num[CPL];
#pragma unroll
    for (int j = 0; j < CPL; ++j) {
        int c = cb + j;
        wp0[j] = Wp[c];
        wp1[j] = Wp[FO + c];
        wp2[j] = Wp[2 * FO + c];
        bpv[j] = bp[c];
        s[j] = 0.f; num[j] = 0.f;
    }
    const uint* av32 = (const uint*)av;
    const int beg = rowp[n], end = rowp[n + 1], last = end - 1;

    uint4 u[NV], un[NV];
    float4 ed, edn;
    {
        const int idx = min(beg + e, last);
        ed = edata[idx];
        const uint* rb = av32 + (size_t)__float_as_int(ed.x) * FO + cb;
#pragma unroll
        for (int q = 0; q < NV; ++q) u[q] = *(const uint4*)(rb + 4 * q);
    }
    for (int base = beg; base < end; base += 4) {
        const int nidx = min(base + 4 + e, last);
        edn = edata[nidx];
        const uint* rb = av32 + (size_t)__float_as_int(edn.x) * FO + cb;
#pragma unroll
        for (int q = 0; q < NV; ++q) un[q] = *(const uint4*)(rb + 4 * q);
        const bool val = (base + e) < end;
        const uint* up = (const uint*)u;
#pragma unroll
        for (int j = 0; j < CPL; ++j) {
            __half2 hv = *(const __half2*)&up[j];
            float as = __half2float(hv.x);
            float vv = __half2float(hv.y);
            float delta = fmaf(ed.y, wp0[j], fmaf(ed.z, wp1[j], fmaf(ed.w, wp2[j], bpv[j])));
            float p = val ? __expf(delta - as) : 0.f;
            s[j] += p;
            num[j] = fmaf(p, vv + delta, num[j]);
        }
        ed = edn;
#pragma unroll
        for (int q = 0; q < NV; ++q) u[q] = un[q];
    }
    // reduce the 4 edge slots
#pragma unroll
    for (int j = 0; j < CPL; ++j) {
        s[j] += __shfl_xor(s[j], 16);
        s[j] += __shfl_xor(s[j], 32);
        num[j] += __shfl_xor(num[j], 16);
        num[j] += __shfl_xor(num[j], 32);
    }
    if (e == 0) {
        ushort o[CPL];
#pragma unroll
        for (int j = 0; j < CPL; ++j) {
            float xi = num[j] / s[j];
            xi = xi > 0.f ? xi : 0.01f * xi;
            __hip_bfloat16 b = __float2bfloat16(xi);
            o[j] = *(ushort*)&b;
        }
        ushort* dst = (ushort*)&h[(size_t)n * HTOT + colbase + cb];
        if (CPL == 4)      *(uint2*)dst = *(uint2*)o;
        else               *(uint4*)dst = *(uint4*)o;
    }
}

// ---------------- launch ----------------

extern "C" void kernel_launch(void* const* d_in, const int* in_sizes, int n_in,
                              void* d_out, int out_size, void* d_ws, size_t ws_size,
                              hipStream_t stream) {
    const float* x = (const float*)d_in[0];
    const int* ei = (const int*)d_in[1];
    const float *Wl[4], *Ws[4], *Wp[4], *bp[4];
    for (int i = 0; i < 4; ++i) {
        Wl[i] = (const float*)d_in[2 + 5 * i];
        Ws[i] = (const float*)d_in[3 + 5 * i];
        Wp[i] = (const float*)d_in[5 + 5 * i];
        bp[i] = (const float*)d_in[6 + 5 * i];
    }
    const float* Wm1 = (const float*)d_in[22];
    const float* bm1 = (const float*)d_in[23];
    const float* Wm2 = (const float*)d_in[24];
    const float* bm2 = (const float*)d_in[25];
    float* out = (float*)d_out;

    char* ws = (char*)d_ws;
    size_t off = 0;
    auto alloc = [&](size_t bytes) -> void* {
        void* p = ws + off;
        off += (bytes + 255) & ~(size_t)255;
        return p;
    };
    __hip_bfloat16* h = (__hip_bfloat16*)alloc((size_t)N_NODES * HTOT * 2);    // 40 MB
    __half* av = (__half*)alloc((size_t)N_NODES * 256 * 2);                    // 25.6 MB
    __hip_bfloat16* Wt = (__hip_bfloat16*)alloc((size_t)384 * 416 * 2);
    int* deg = (int*)alloc((size_t)N_NODES * 4);
    int* rowp = (int*)alloc((size_t)(N_NODES + 1) * 4);
    int* cursor = (int*)alloc((size_t)N_NODES * 4);
    int* bsum = (int*)alloc((size_t)(NSCB + 1) * 4);
    float4* edata = (float4*)alloc((size_t)ET * 16);                           // 13.6 MB
    (void)ws_size; (void)n_in; (void)in_sizes; (void)out_size;

    hipMemsetAsync(deg, 0, (size_t)N_NODES * 4, stream);
    copy_x_kernel<<<(N_NODES * 16 + 255) / 256, 256, 0, stream>>>(x, h);
    hist_kernel<<<(ET + 255) / 256, 256, 0, stream>>>(ei, deg);
    scan_p1<<<NSCB, 256, 0, stream>>>(deg, bsum);
    scan_p2<<<1, 64, 0, stream>>>(bsum);
    scan_p3<<<NSCB, 256, 0, stream>>>(deg, bsum, rowp, cursor);
    scatter_kernel<<<(ET + 255) / 256, 256, 0, stream>>>(ei, x, cursor, edata);

    const int M = N_NODES;
    const int gx = (M + 127) / 128;
    const int nbn = (N_NODES + 3) / 4;       // node-blocks (4 waves/block, 1 node/wave)
    for (int L = 0; L < 4; ++L) {
        const int K = INS_h[L], K32 = K32_h[L], fo = HO_h[L], n2 = 2 * fo;
        const int total = n2 * K32;
        concat_wT_kernel<<<(total + 255) / 256, 256, 0, stream>>>(Ws[L], Wl[L],
                                                                  K, K32, fo, Wt, total);
        dim3 g(gx, n2 / 64);
        gemm3_kernel<false><<<g, 256, 0, stream>>>(h, HTOT, Wt, K32, nullptr, av, fo,
                                                   M, K, nullptr, nullptr, nullptr);
        if (fo == 64)
            attn_kernel<4><<<nbn, 256, 0, stream>>>(h, av, Wp[L], bp[L], rowp, edata, K);
        else
            attn_kernel<8><<<nbn, 256, 0, stream>>>(h, av, Wp[L], bp[L], rowp, edata, K);
    }
    {
        const int total = 64 * 416;
        concat_wT_kernel<<<(total + 255) / 256, 256, 0, stream>>>(Wm1, nullptr,
                                                                  400, 416, 64, Wt, total);
        gemm3_kernel<true><<<dim3(gx, 1), 256, 0, stream>>>(h, HTOT, Wt, 416, bm1,
                                                            nullptr, 0, M, 400, Wm2, bm2, out);
    }
}

// Round 10
// 386.886 us; speedup vs baseline: 4.3470x; 1.0383x over previous
//
#include <hip/hip_runtime.h>
#include <hip/hip_bf16.h>
#include <hip/hip_fp16.h>
#include <math.h>

#define N_NODES 50000
#define N_EDGES 800000
#define ET (N_EDGES + N_NODES)
#define HTOT 400

#define SCAN_CHUNK 1024
#define NSCB ((N_NODES + SCAN_CHUNK - 1) / SCAN_CHUNK)   // 49

typedef __attribute__((ext_vector_type(4))) float f32x4;
typedef __attribute__((ext_vector_type(8))) short bf16x8;

static const int INS_h[4] = {16, 80, 144, 272};
static const int K32_h[4] = {32, 96, 160, 288};
static const int HO_h[4]  = {64, 64, 128, 128};

#define LOG2E_F 1.4426950408889634f

// ---------------- fused prep: copy_x + deg zero + all weight concats ----------------
// regions (thread index): [0,800000) copy_x ; [..+50000) deg=0 ; then 5 concat regions.

struct PrepArgs {
    const float* x; __hip_bfloat16* h; int* deg;
    const float* Ws0; const float* Wl0;
    const float* Ws1; const float* Wl1;
    const float* Ws2; const float* Wl2;
    const float* Ws3; const float* Wl3;
    const float* Wm1;
    __hip_bfloat16* Wt0; __hip_bfloat16* Wt1; __hip_bfloat16* Wt2;
    __hip_bfloat16* Wt3; __hip_bfloat16* WtF;
};

__device__ inline void concat1(const float* __restrict__ W0, const float* __restrict__ W1,
                               int K, int K32, int fo, __hip_bfloat16* __restrict__ Wt, int i) {
    int c = i / K32, kk = i - c * K32;
    float v = 0.f;
    if (kk < K) v = (c < fo) ? W0[kk * fo + c] : W1[kk * fo + (c - fo)];
    Wt[i] = __float2bfloat16(v);
}

#define PREP_TOTAL 1007696

__global__ __launch_bounds__(256) void prep_kernel(PrepArgs a) {
    int i = blockIdx.x * 256 + threadIdx.x;
    if (i < 800000) {
        int n = i >> 4, c = i & 15;
        a.h[n * HTOT + c] = __float2bfloat16(a.x[i]);
        return;
    }
    i -= 800000;
    if (i < 50000) { a.deg[i] = 0; return; }
    i -= 50000;
    if (i < 4096)  { concat1(a.Ws0, a.Wl0, 16, 32, 64, a.Wt0, i); return; }
    i -= 4096;
    if (i < 12288) { concat1(a.Ws1, a.Wl1, 80, 96, 64, a.Wt1, i); return; }
    i -= 12288;
    if (i < 40960) { concat1(a.Ws2, a.Wl2, 144, 160, 128, a.Wt2, i); return; }
    i -= 40960;
    if (i < 73728) { concat1(a.Ws3, a.Wl3, 272, 288, 128, a.Wt3, i); return; }
    i -= 73728;
    if (i < 26624) {
        int c = i / 416, kk = i - c * 416;
        float v = (kk < 400) ? a.Wm1[kk * 64 + c] : 0.f;
        a.WtF[i] = __float2bfloat16(v);
    }
}

// ---------------- CSR build ----------------

__global__ void hist_kernel(const int* __restrict__ ei, int* __restrict__ deg) {
    int e = blockIdx.x * blockDim.x + threadIdx.x;
    if (e >= ET) return;
    int dst = (e < N_EDGES) ? ei[N_EDGES + e] : (e - N_EDGES);
    atomicAdd(&deg[dst], 1);
}

__global__ __launch_bounds__(256) void scan_p1(const int* __restrict__ deg,
                                               int* __restrict__ bsum) {
    __shared__ int red[256];
    const int b = blockIdx.x, t = threadIdx.x;
    const int base = b * SCAN_CHUNK + t * 4;
    int s = 0;
#pragma unroll
    for (int j = 0; j < 4; ++j) {
        int i = base + j;
        if (i < N_NODES) s += deg[i];
    }
    red[t] = s;
    __syncthreads();
    for (int off = 128; off > 0; off >>= 1) {
        if (t < off) red[t] += red[t + off];
        __syncthreads();
    }
    if (t == 0) bsum[b] = red[0];
}

__global__ void scan_p2(int* __restrict__ bsum) {
    const int lane = threadIdx.x;            // blockDim = 64
    int v = (lane < NSCB) ? bsum[lane] : 0;
    int inc = v;
#pragma unroll
    for (int off = 1; off < 64; off <<= 1) {
        int u = __shfl_up(inc, off);
        if (lane >= off) inc += u;
    }
    if (lane < NSCB) bsum[lane] = inc - v;   // exclusive
    if (lane == 63) bsum[NSCB] = inc;        // grand total
}

__global__ __launch_bounds__(256) void scan_p3(const int* __restrict__ deg,
                                               const int* __restrict__ bsum,
                                               int* __restrict__ row_ptr,
                                               int* __restrict__ cursor) {
    __shared__ int ts[256];
    const int b = blockIdx.x, t = threadIdx.x;
    const int base = b * SCAN_CHUNK + t * 4;
    int v[4];
    int s = 0;
#pragma unroll
    for (int j = 0; j < 4; ++j) {
        int i = base + j;
        v[j] = (i < N_NODES) ? deg[i] : 0;
        s += v[j];
    }
    ts[t] = s;
    __syncthreads();
    for (int off = 1; off < 256; off <<= 1) {
        int u = (t >= off) ? ts[t - off] : 0;
        __syncthreads();
        ts[t] += u;
        __syncthreads();
    }
    int excl = bsum[b] + ts[t] - s;
#pragma unroll
    for (int j = 0; j < 4; ++j) {
        int i = base + j;
        if (i < N_NODES) {
            row_ptr[i] = excl;
            cursor[i] = excl;
            excl += v[j];
        }
    }
    if (b == 0 && t == 0) row_ptr[N_NODES] = bsum[NSCB];
}

__global__ void scatter_kernel(const int* __restrict__ ei, const float* __restrict__ x,
                               int* __restrict__ cursor, float4* __restrict__ edata) {
    int e = blockIdx.x * blockDim.x + threadIdx.x;
    if (e >= ET) return;
    int src, dst;
    if (e < N_EDGES) { src = ei[e]; dst = ei[N_EDGES + e]; }
    else             { src = dst = e - N_EDGES; }
    int p = atomicAdd(&cursor[dst], 1);
    float dx = x[dst * 16 + 0] - x[src * 16 + 0];
    float dy = x[dst * 16 + 1] - x[src * 16 + 1];
    float dz = x[dst * 16 + 2] - x[src * 16 + 2];
    edata[p] = make_float4(__int_as_float(src), dx, dy, dz);
}

// ---------------- bf16 MFMA GEMM: C[M x N] = A[M x K] * W[K x N], fp32 accum ----------------
// A bf16 [M][lda], Wt bf16 [N][K32] (transposed, zero-padded). BM=128 BN=64 BK=32, 4 waves.
// !FUSE: N==2*fo; epilogue writes av[row][2*fo] fp16: cols [0,fo) hold -a_src*log2e
// (prescaled for exp2), cols [fo,2fo) hold v.
// FUSE: N==64: epilogue out = (C+bias) @ W2 + b2 (64->8), fp32.

template <bool FUSE>
__global__ __launch_bounds__(256) void gemm3_kernel(
    const __hip_bfloat16* __restrict__ A, int lda,
    const __hip_bfloat16* __restrict__ Wt, int K32,
    const float* __restrict__ bias,
    __half* __restrict__ av, int fo,
    int M, int K,
    const float* __restrict__ W2, const float* __restrict__ b2,
    float* __restrict__ out) {
    __shared__ float smemf[9728];                 // 38.9 KB, aliased below
    ushort* sA = (ushort*)smemf;                  // [2][128*40] bf16
    ushort* sB = (ushort*)smemf + 10240;          // [2][64*40]
    const int t = threadIdx.x;
    const int r0 = blockIdx.x * 128, c0 = blockIdx.y * 64;
    const int w = t >> 6, lane = t & 63;
    const int l15 = lane & 15, l4 = lane >> 4;

    f32x4 acc[2][4];
#pragma unroll
    for (int i = 0; i < 2; ++i)
#pragma unroll
        for (int j = 0; j < 4; ++j) acc[i][j] = (f32x4){0.f, 0.f, 0.f, 0.f};

    const int sr = t >> 2, sq = (t & 3) * 8;
    const int ar1 = min(r0 + sr, M - 1), ar2 = min(r0 + sr + 64, M - 1);
    const size_t a1b = (size_t)ar1 * lda, a2b = (size_t)ar2 * lda;
    const size_t wb = (size_t)(c0 + sr) * K32;
    const int nk = K32 >> 5;

    uint4 ga0, ga1, gb;
    const uint4 z4 = {0u, 0u, 0u, 0u};
    {
        const int kk = sq;
        const bool ok = kk < K;
        ga0 = ok ? *(const uint4*)(A + a1b + kk) : z4;
        ga1 = ok ? *(const uint4*)(A + a2b + kk) : z4;
        gb  = *(const uint4*)(Wt + wb + kk);
        *(uint4*)(sA + sr * 40 + sq) = ga0;
        *(uint4*)(sA + (sr + 64) * 40 + sq) = ga1;
        *(uint4*)(sB + sr * 40 + sq) = gb;
    }
    __syncthreads();

    int buf = 0;
    for (int kc = 0; kc < nk; ++kc) {
        const bool nx = (kc + 1) < nk;
        if (nx) {
            const int kk = (kc + 1) * 32 + sq;
            const bool ok = kk < K;
            ga0 = ok ? *(const uint4*)(A + a1b + kk) : z4;
            ga1 = ok ? *(const uint4*)(A + a2b + kk) : z4;
            gb  = *(const uint4*)(Wt + wb + kk);
        }
        const ushort* bA = sA + buf * 5120 + w * 1280;
        const ushort* bB = sB + buf * 2560;
        bf16x8 af[2], bfr[4];
#pragma unroll
        for (int i = 0; i < 2; ++i)
            af[i] = *(const bf16x8*)(bA + (i * 16 + l15) * 40 + l4 * 8);
#pragma unroll
        for (int j = 0; j < 4; ++j)
            bfr[j] = *(const bf16x8*)(bB + (j * 16 + l15) * 40 + l4 * 8);
#pragma unroll
        for (int i = 0; i < 2; ++i)
#pragma unroll
            for (int j = 0; j < 4; ++j)
                acc[i][j] = __builtin_amdgcn_mfma_f32_16x16x32_bf16(af[i], bfr[j], acc[i][j], 0, 0, 0);
        if (nx) {
            const int ob = buf ^ 1;
            *(uint4*)(sA + ob * 5120 + sr * 40 + sq) = ga0;
            *(uint4*)(sA + ob * 5120 + (sr + 64) * 40 + sq) = ga1;
            *(uint4*)(sB + ob * 2560 + sr * 40 + sq) = gb;
        }
        __syncthreads();
        buf ^= 1;
    }

    if (!FUSE) {
        const int n2 = 2 * fo;
#pragma unroll
        for (int i = 0; i < 2; ++i)
#pragma unroll
            for (int j = 0; j < 4; ++j)
#pragma unroll
                for (int p = 0; p < 4; ++p) {
                    int row = r0 + w * 32 + i * 16 + l4 * 4 + p;
                    int col = c0 + j * 16 + l15;          // in [0, 2*fo)
                    if (row < M) {
                        float vv = acc[i][j][p];
                        if (col < fo) vv *= -LOG2E_F;     // a-slot: prescaled for exp2
                        av[(size_t)row * n2 + col] = __float2half(vv);
                    }
                }
    } else {
#pragma unroll
        for (int i = 0; i < 2; ++i)
#pragma unroll
            for (int j = 0; j < 4; ++j)
#pragma unroll
                for (int p = 0; p < 4; ++p) {
                    int lrow = w * 32 + i * 16 + l4 * 4 + p;
                    int col = j * 16 + l15;
                    smemf[lrow * 68 + col] = acc[i][j][p] + bias[col];
                }
        smemf[8704 + t] = W2[t];
        smemf[8704 + 256 + t] = W2[256 + t];
        __syncthreads();
        const int row = t >> 1, oc = (t & 1) * 4;
        f32x4 o = *(const f32x4*)&b2[oc];
#pragma unroll 8
        for (int k = 0; k < 64; ++k) {
            float a = smemf[row * 68 + k];
            o += a * *(const f32x4*)&smemf[8704 + k * 8 + oc];
        }
        const int grow = r0 + row;
        if (grow < M) *(f32x4*)&out[(size_t)grow * 8 + oc] = o;
    }
}

// ---------------- attention: one wave per node; 4 edge slots x 16 lanes; packed fp16 ----------------
// av row: [0,fo) = -a_src*log2e (fp16), [fo,2fo) = v (fp16).
// p = exp2(delta*log2e - a_src*log2e) = exp(delta - a_src); a_dst cancels in the softmax.
// Inner math in packed fp16 (v_pk_fma_f16); exp + accumulators in fp32.

template <int CPL>   // 4 (fo=64) or 8 (fo=128)
__global__ __launch_bounds__(256) void attn_kernel(
    __hip_bfloat16* __restrict__ h,
    const __half* __restrict__ av,
    const float* __restrict__ Wp, const float* __restrict__ bp,
    const int* __restrict__ rowp, const float4* __restrict__ edata,
    int colbase) {
    constexpr int FO = 16 * CPL;
    constexpr int NU = CPL / 2;            // uints (half2 pairs) per region per lane
    const int wid = (blockIdx.x * (int)blockDim.x + (int)threadIdx.x) >> 6;
    if (wid >= N_NODES) return;
    const int lane = threadIdx.x & 63;
    const int e = lane >> 4, l16 = lane & 15;
    const int n = wid;
    const int cb = l16 * CPL;
    const int cb2 = cb >> 1;

    __half2 wp0h[NU], wp1h[NU], wp2h[NU], bph[NU];
#pragma unroll
    for (int jj = 0; jj < NU; ++jj) {
        int c = cb + 2 * jj;
        wp0h[jj] = __floats2half2_rn(Wp[c], Wp[c + 1]);
        wp1h[jj] = __floats2half2_rn(Wp[FO + c], Wp[FO + c + 1]);
        wp2h[jj] = __floats2half2_rn(Wp[2 * FO + c], Wp[2 * FO + c + 1]);
        bph[jj]  = __floats2half2_rn(bp[c], bp[c + 1]);
    }
    float s[CPL], num[CPL];
#pragma unroll
    for (int j = 0; j < CPL; ++j) { s[j] = 0.f; num[j] = 0.f; }

    const uint* avu = (const uint*)av;     // FO uints per node row (2*FO halves)
    const __half2 L2E = __float2half2_rn(LOG2E_F);
    const int beg = rowp[n], end = rowp[n + 1], last = end - 1;

    uint as_c[NU], vv_c[NU], as_n[NU], vv_n[NU];
    float4 ed, edn;

    auto ld = [&](int idx, float4& edo, uint* as, uint* vv) {
        edo = edata[idx];
        const uint* rb = avu + (size_t)__float_as_int(edo.x) * FO;
        if (CPL == 8) {
            uint4 a = *(const uint4*)(rb + cb2);
            uint4 v = *(const uint4*)(rb + FO / 2 + cb2);
            as[0] = a.x; as[1] = a.y; as[2] = a.z; as[3] = a.w;
            vv[0] = v.x; vv[1] = v.y; vv[2] = v.z; vv[3] = v.w;
        } else {
            uint2 a = *(const uint2*)(rb + cb2);
            uint2 v = *(const uint2*)(rb + FO / 2 + cb2);
            as[0] = a.x; as[1] = a.y;
            vv[0] = v.x; vv[1] = v.y;
        }
    };

    ld(min(beg + e, last), ed, as_c, vv_c);
    for (int base = beg; base < end; base += 4) {
        ld(min(base + 4 + e, last), edn, as_n, vv_n);
        const bool val = (base + e) < end;
        __half2 yh = __float2half2_rn(ed.y);
        __half2 zh = __float2half2_rn(ed.z);
        __half2 wh = __float2half2_rn(ed.w);
#pragma unroll
        for (int jj = 0; jj < NU; ++jj) {
            __half2 d  = __hfma2(yh, wp0h[jj], __hfma2(zh, wp1h[jj], __hfma2(wh, wp2h[jj], bph[jj])));
            __half2 a2 = __hfma2(d, L2E, *(const __half2*)&as_c[jj]);
            __half2 vd = __hadd2(*(const __half2*)&vv_c[jj], d);
            float pl = exp2f(__half2float(__low2half(a2)));
            float ph = exp2f(__half2float(__high2half(a2)));
            pl = val ? pl : 0.f;
            ph = val ? ph : 0.f;
            s[2 * jj]     += pl;
            s[2 * jj + 1] += ph;
            num[2 * jj]     = fmaf(pl, __half2float(__low2half(vd)),  num[2 * jj]);
            num[2 * jj + 1] = fmaf(ph, __half2float(__high2half(vd)), num[2 * jj + 1]);
        }
        ed = edn;
#pragma unroll
        for (int q = 0; q < NU; ++q) { as_c[q] = as_n[q]; vv_c[q] = vv_n[q]; }
    }
    // reduce the 4 edge slots
#pragma unroll
    for (int j = 0; j < CPL; ++j) {
        s[j] += __shfl_xor(s[j], 16);
        s[j] += __shfl_xor(s[j], 32);
        num[j] += __shfl_xor(num[j], 16);
        num[j] += __shfl_xor(num[j], 32);
    }
    if (e == 0) {
        ushort o[CPL];
#pragma unroll
        for (int j = 0; j < CPL; ++j) {
            float xi = num[j] / s[j];
            xi = xi > 0.f ? xi : 0.01f * xi;
            __hip_bfloat16 b = __float2bfloat16(xi);
            o[j] = *(ushort*)&b;
        }
        ushort* dst = (ushort*)&h[(size_t)n * HTOT + colbase + cb];
        if (CPL == 4)      *(uint2*)dst = *(uint2*)o;
        else               *(uint4*)dst = *(uint4*)o;
    }
}

// ---------------- launch ----------------

extern "C" void kernel_launch(void* const* d_in, const int* in_sizes, int n_in,
                              void* d_out, int out_size, void* d_ws, size_t ws_size,
                              hipStream_t stream) {
    const float* x = (const float*)d_in[0];
    const int* ei = (const int*)d_in[1];
    const float *Wl[4], *Ws[4], *Wp[4], *bp[4];
    for (int i = 0; i < 4; ++i) {
        Wl[i] = (const float*)d_in[2 + 5 * i];
        Ws[i] = (const float*)d_in[3 + 5 * i];
        Wp[i] = (const float*)d_in[5 + 5 * i];
        bp[i] = (const float*)d_in[6 + 5 * i];
    }
    const float* Wm1 = (const float*)d_in[22];
    const float* bm1 = (const float*)d_in[23];
    const float* Wm2 = (const float*)d_in[24];
    const float* bm2 = (const float*)d_in[25];
    float* out = (float*)d_out;

    char* ws = (char*)d_ws;
    size_t off = 0;
    auto alloc = [&](size_t bytes) -> void* {
        void* p = ws + off;
        off += (bytes + 255) & ~(size_t)255;
        return p;
    };
    __hip_bfloat16* h = (__hip_bfloat16*)alloc((size_t)N_NODES * HTOT * 2);    // 40 MB
    __half* av = (__half*)alloc((size_t)N_NODES * 256 * 2);                    // 25.6 MB
    __hip_bfloat16* Wt0 = (__hip_bfloat16*)alloc((size_t)4096 * 2);
    __hip_bfloat16* Wt1 = (__hip_bfloat16*)alloc((size_t)12288 * 2);
    __hip_bfloat16* Wt2 = (__hip_bfloat16*)alloc((size_t)40960 * 2);
    __hip_bfloat16* Wt3 = (__hip_bfloat16*)alloc((size_t)73728 * 2);
    __hip_bfloat16* WtF = (__hip_bfloat16*)alloc((size_t)26624 * 2);
    int* deg = (int*)alloc((size_t)N_NODES * 4);
    int* rowp = (int*)alloc((size_t)(N_NODES + 1) * 4);
    int* cursor = (int*)alloc((size_t)N_NODES * 4);
    int* bsum = (int*)alloc((size_t)(NSCB + 1) * 4);
    float4* edata = (float4*)alloc((size_t)ET * 16);                           // 13.6 MB
    (void)ws_size; (void)n_in; (void)in_sizes; (void)out_size;

    PrepArgs pa;
    pa.x = x; pa.h = h; pa.deg = deg;
    pa.Ws0 = Ws[0]; pa.Wl0 = Wl[0];
    pa.Ws1 = Ws[1]; pa.Wl1 = Wl[1];
    pa.Ws2 = Ws[2]; pa.Wl2 = Wl[2];
    pa.Ws3 = Ws[3]; pa.Wl3 = Wl[3];
    pa.Wm1 = Wm1;
    pa.Wt0 = Wt0; pa.Wt1 = Wt1; pa.Wt2 = Wt2; pa.Wt3 = Wt3; pa.WtF = WtF;
    prep_kernel<<<(PREP_TOTAL + 255) / 256, 256, 0, stream>>>(pa);

    hist_kernel<<<(ET + 255) / 256, 256, 0, stream>>>(ei, deg);
    scan_p1<<<NSCB, 256, 0, stream>>>(deg, bsum);
    scan_p2<<<1, 64, 0, stream>>>(bsum);
    scan_p3<<<NSCB, 256, 0, stream>>>(deg, bsum, rowp, cursor);
    scatter_kernel<<<(ET + 255) / 256, 256, 0, stream>>>(ei, x, cursor, edata);

    const int M = N_NODES;
    const int gx = (M + 127) / 128;
    const int nbn = (N_NODES + 3) / 4;       // node-blocks (4 waves/block, 1 node/wave)
    __hip_bfloat16* Wts[4] = {Wt0, Wt1, Wt2, Wt3};
    for (int L = 0; L < 4; ++L) {
        const int K = INS_h[L], K32 = K32_h[L], fo = HO_h[L], n2 = 2 * fo;
        dim3 g(gx, n2 / 64);
        gemm3_kernel<false><<<g, 256, 0, stream>>>(h, HTOT, Wts[L], K32, nullptr, av, fo,
                                                   M, K, nullptr, nullptr, nullptr);
        if (fo == 64)
            attn_kernel<4><<<nbn, 256, 0, stream>>>(h, av, Wp[L], bp[L], rowp, edata, K);
        else
            attn_kernel<8><<<nbn, 256, 0, stream>>>(h, av, Wp[L], bp[L], rowp, edata, K);
    }
    gemm3_kernel<true><<<dim3(gx, 1), 256, 0, stream>>>(h, HTOT, WtF, 416, bm1,
                                                        nullptr, 0, M, 400, Wm2, bm2, out);
}

// Round 11
// 358.424 us; speedup vs baseline: 4.6922x; 1.0794x over previous
//
#include <hip/hip_runtime.h>
#include <hip/hip_bf16.h>
#include <hip/hip_fp16.h>
#include <math.h>

#define N_NODES 50000
#define N_EDGES 800000
#define ET (N_EDGES + N_NODES)
#define HTOT 400

#define SCAN_CHUNK 1024
#define NSCB ((N_NODES + SCAN_CHUNK - 1) / SCAN_CHUNK)   // 49

typedef __attribute__((ext_vector_type(4))) float f32x4;
typedef __attribute__((ext_vector_type(8))) short bf16x8;

static const int INS_h[4] = {16, 80, 144, 272};
static const int K32_h[4] = {32, 96, 160, 288};
static const int HO_h[4]  = {64, 64, 128, 128};

#define LOG2E_F 1.4426950408889634f

// ---------------- fused prep: copy_x + deg zero + all weight concats ----------------

struct PrepArgs {
    const float* x; __hip_bfloat16* h; int* deg;
    const float* Ws0; const float* Wl0;
    const float* Ws1; const float* Wl1;
    const float* Ws2; const float* Wl2;
    const float* Ws3; const float* Wl3;
    const float* Wm1;
    __hip_bfloat16* Wt0; __hip_bfloat16* Wt1; __hip_bfloat16* Wt2;
    __hip_bfloat16* Wt3; __hip_bfloat16* WtF;
};

__device__ inline void concat1(const float* __restrict__ W0, const float* __restrict__ W1,
                               int K, int K32, int fo, __hip_bfloat16* __restrict__ Wt, int i) {
    int c = i / K32, kk = i - c * K32;
    float v = 0.f;
    if (kk < K) v = (c < fo) ? W0[kk * fo + c] : W1[kk * fo + (c - fo)];
    Wt[i] = __float2bfloat16(v);
}

#define PREP_TOTAL 1007696

__global__ __launch_bounds__(256) void prep_kernel(PrepArgs a) {
    int i = blockIdx.x * 256 + threadIdx.x;
    if (i < 800000) {
        int n = i >> 4, c = i & 15;
        a.h[n * HTOT + c] = __float2bfloat16(a.x[i]);
        return;
    }
    i -= 800000;
    if (i < 50000) { a.deg[i] = 0; return; }
    i -= 50000;
    if (i < 4096)  { concat1(a.Ws0, a.Wl0, 16, 32, 64, a.Wt0, i); return; }
    i -= 4096;
    if (i < 12288) { concat1(a.Ws1, a.Wl1, 80, 96, 64, a.Wt1, i); return; }
    i -= 12288;
    if (i < 40960) { concat1(a.Ws2, a.Wl2, 144, 160, 128, a.Wt2, i); return; }
    i -= 40960;
    if (i < 73728) { concat1(a.Ws3, a.Wl3, 272, 288, 128, a.Wt3, i); return; }
    i -= 73728;
    if (i < 26624) {
        int c = i / 416, kk = i - c * 416;
        float v = (kk < 400) ? a.Wm1[kk * 64 + c] : 0.f;
        a.WtF[i] = __float2bfloat16(v);
    }
}

// ---------------- CSR build ----------------

__global__ void hist_kernel(const int* __restrict__ ei, int* __restrict__ deg) {
    int e = blockIdx.x * blockDim.x + threadIdx.x;
    if (e >= ET) return;
    int dst = (e < N_EDGES) ? ei[N_EDGES + e] : (e - N_EDGES);
    atomicAdd(&deg[dst], 1);
}

__global__ __launch_bounds__(256) void scan_p1(const int* __restrict__ deg,
                                               int* __restrict__ bsum) {
    __shared__ int red[256];
    const int b = blockIdx.x, t = threadIdx.x;
    const int base = b * SCAN_CHUNK + t * 4;
    int s = 0;
#pragma unroll
    for (int j = 0; j < 4; ++j) {
        int i = base + j;
        if (i < N_NODES) s += deg[i];
    }
    red[t] = s;
    __syncthreads();
    for (int off = 128; off > 0; off >>= 1) {
        if (t < off) red[t] += red[t + off];
        __syncthreads();
    }
    if (t == 0) bsum[b] = red[0];
}

// p3 with p2 folded in: each block redundantly wave-scans the 49 block sums.
__global__ __launch_bounds__(256) void scan_p3(const int* __restrict__ deg,
                                               const int* __restrict__ bsum,
                                               int* __restrict__ row_ptr,
                                               int* __restrict__ cursor) {
    __shared__ int ts[256];
    __shared__ int sb[2];     // [0] = exclusive prefix for this block, [1] = total
    const int b = blockIdx.x, t = threadIdx.x;
    if (t < 64) {
        int v = (t < NSCB) ? bsum[t] : 0;
        int inc = v;
#pragma unroll
        for (int off = 1; off < 64; off <<= 1) {
            int u = __shfl_up(inc, off);
            if (t >= off) inc += u;
        }
        if (t == b) sb[0] = inc - v;
        if (t == 63) sb[1] = inc;
    }
    const int base = b * SCAN_CHUNK + t * 4;
    int v[4];
    int s = 0;
#pragma unroll
    for (int j = 0; j < 4; ++j) {
        int i = base + j;
        v[j] = (i < N_NODES) ? deg[i] : 0;
        s += v[j];
    }
    ts[t] = s;
    __syncthreads();
    for (int off = 1; off < 256; off <<= 1) {
        int u = (t >= off) ? ts[t - off] : 0;
        __syncthreads();
        ts[t] += u;
        __syncthreads();
    }
    int excl = sb[0] + ts[t] - s;
#pragma unroll
    for (int j = 0; j < 4; ++j) {
        int i = base + j;
        if (i < N_NODES) {
            row_ptr[i] = excl;
            cursor[i] = excl;
            excl += v[j];
        }
    }
    if (b == 0 && t == 0) row_ptr[N_NODES] = sb[1];
}

// edata entry (8 B): x = src(16b) | dz_fp16(16b) ; y = half2(dx, dy)
__global__ void scatter_kernel(const int* __restrict__ ei, const float* __restrict__ x,
                               int* __restrict__ cursor, uint2* __restrict__ edata) {
    int e = blockIdx.x * blockDim.x + threadIdx.x;
    if (e >= ET) return;
    int src, dst;
    if (e < N_EDGES) { src = ei[e]; dst = ei[N_EDGES + e]; }
    else             { src = dst = e - N_EDGES; }
    int p = atomicAdd(&cursor[dst], 1);
    float4 pd = *(const float4*)&x[dst * 16];
    float4 ps = *(const float4*)&x[src * 16];
    __half dxh = __float2half(pd.x - ps.x);
    __half dyh = __float2half(pd.y - ps.y);
    __half dzh = __float2half(pd.z - ps.z);
    uint w0 = (uint)src | ((uint)__half_as_ushort(dzh) << 16);
    __half2 xy;
    xy.x = dxh; xy.y = dyh;
    edata[p] = make_uint2(w0, *(uint*)&xy);
}

// ---------------- bf16 MFMA GEMM: C[M x N] = A[M x K] * W[K x N], fp32 accum ----------------
// 1D grid, GXP (multiple of 8) row-blocks: bid -> gxp = bid%GXP (same gxp => same XCD =>
// A-tile L2 reuse across the gy column blocks), gy = bid/GXP.
// !FUSE: N==2*fo; av[row][2*fo] fp16: cols [0,fo) = -a_src*log2e, [fo,2fo) = v.
// FUSE: N==64: epilogue out = (C+bias) @ W2 + b2 (64->8), fp32.

template <bool FUSE>
__global__ __launch_bounds__(256) void gemm3_kernel(
    const __hip_bfloat16* __restrict__ A, int lda,
    const __hip_bfloat16* __restrict__ Wt, int K32,
    const float* __restrict__ bias,
    __half* __restrict__ av, int fo,
    int M, int K, int GXP,
    const float* __restrict__ W2, const float* __restrict__ b2,
    float* __restrict__ out) {
    __shared__ float smemf[9728];                 // 38.9 KB, aliased below
    ushort* sA = (ushort*)smemf;                  // [2][128*40] bf16
    ushort* sB = (ushort*)smemf + 10240;          // [2][64*40]
    const int t = threadIdx.x;
    const int bid = blockIdx.x;
    const int gxp = bid % GXP;
    const int gy = bid / GXP;
    const int r0 = gxp * 128, c0 = gy * 64;
    const int w = t >> 6, lane = t & 63;
    const int l15 = lane & 15, l4 = lane >> 4;

    f32x4 acc[2][4];
#pragma unroll
    for (int i = 0; i < 2; ++i)
#pragma unroll
        for (int j = 0; j < 4; ++j) acc[i][j] = (f32x4){0.f, 0.f, 0.f, 0.f};

    const int sr = t >> 2, sq = (t & 3) * 8;
    const int ar1 = min(r0 + sr, M - 1), ar2 = min(r0 + sr + 64, M - 1);
    const size_t a1b = (size_t)ar1 * lda, a2b = (size_t)ar2 * lda;
    const size_t wb = (size_t)(c0 + sr) * K32;
    const int nk = K32 >> 5;

    uint4 ga0, ga1, gb;
    const uint4 z4 = {0u, 0u, 0u, 0u};
    {
        const int kk = sq;
        const bool ok = kk < K;
        ga0 = ok ? *(const uint4*)(A + a1b + kk) : z4;
        ga1 = ok ? *(const uint4*)(A + a2b + kk) : z4;
        gb  = *(const uint4*)(Wt + wb + kk);
        *(uint4*)(sA + sr * 40 + sq) = ga0;
        *(uint4*)(sA + (sr + 64) * 40 + sq) = ga1;
        *(uint4*)(sB + sr * 40 + sq) = gb;
    }
    __syncthreads();

    int buf = 0;
    for (int kc = 0; kc < nk; ++kc) {
        const bool nx = (kc + 1) < nk;
        if (nx) {
            const int kk = (kc + 1) * 32 + sq;
            const bool ok = kk < K;
            ga0 = ok ? *(const uint4*)(A + a1b + kk) : z4;
            ga1 = ok ? *(const uint4*)(A + a2b + kk) : z4;
            gb  = *(const uint4*)(Wt + wb + kk);
        }
        const ushort* bA = sA + buf * 5120 + w * 1280;
        const ushort* bB = sB + buf * 2560;
        bf16x8 af[2], bfr[4];
#pragma unroll
        for (int i = 0; i < 2; ++i)
            af[i] = *(const bf16x8*)(bA + (i * 16 + l15) * 40 + l4 * 8);
#pragma unroll
        for (int j = 0; j < 4; ++j)
            bfr[j] = *(const bf16x8*)(bB + (j * 16 + l15) * 40 + l4 * 8);
#pragma unroll
        for (int i = 0; i < 2; ++i)
#pragma unroll
            for (int j = 0; j < 4; ++j)
                acc[i][j] = __builtin_amdgcn_mfma_f32_16x16x32_bf16(af[i], bfr[j], acc[i][j], 0, 0, 0);
        if (nx) {
            const int ob = buf ^ 1;
            *(uint4*)(sA + ob * 5120 + sr * 40 + sq) = ga0;
            *(uint4*)(sA + ob * 5120 + (sr + 64) * 40 + sq) = ga1;
            *(uint4*)(sB + ob * 2560 + sr * 40 + sq) = gb;
        }
        __syncthreads();
        buf ^= 1;
    }

    if (!FUSE) {
        const int n2 = 2 * fo;
#pragma unroll
        for (int i = 0; i < 2; ++i)
#pragma unroll
            for (int j = 0; j < 4; ++j)
#pragma unroll
                for (int p = 0; p < 4; ++p) {
                    int row = r0 + w * 32 + i * 16 + l4 * 4 + p;
                    int col = c0 + j * 16 + l15;          // in [0, 2*fo)
                    if (row < M) {
                        float vv = acc[i][j][p];
                        if (col < fo) vv *= -LOG2E_F;     // a-slot: prescaled for exp2
                        av[(size_t)row * n2 + col] = __float2half(vv);
                    }
                }
    } else {
#pragma unroll
        for (int i = 0; i < 2; ++i)
#pragma unroll
            for (int j = 0; j < 4; ++j)
#pragma unroll
                for (int p = 0; p < 4; ++p) {
                    int lrow = w * 32 + i * 16 + l4 * 4 + p;
                    int col = j * 16 + l15;
                    smemf[lrow * 68 + col] = acc[i][j][p] + bias[col];
                }
        smemf[8704 + t] = W2[t];
        smemf[8704 + 256 + t] = W2[256 + t];
        __syncthreads();
        const int row = t >> 1, oc = (t & 1) * 4;
        f32x4 o = *(const f32x4*)&b2[oc];
#pragma unroll 8
        for (int k = 0; k < 64; ++k) {
            float a = smemf[row * 68 + k];
            o += a * *(const f32x4*)&smemf[8704 + k * 8 + oc];
        }
        const int grow = r0 + row;
        if (grow < M) *(f32x4*)&out[(size_t)grow * 8 + oc] = o;
    }
}

// ---------------- attention: one wave per node; SLOTS edge slots x LPE lanes; CPL=8 ----------------
// av row: [0,fo) = -a_src*log2e (fp16), [fo,2fo) = v (fp16).
// p = exp2(delta*log2e - a_src*log2e); a_dst cancels in the per-dst softmax.
// Invalid tail slots: a-word replaced by -inf half2 -> p = 0 exactly.

template <int LPE>   // lanes per edge: 8 (fo=64) or 16 (fo=128); 8 channels per lane
__global__ __launch_bounds__(256) void attn_kernel(
    __hip_bfloat16* __restrict__ h,
    const __half* __restrict__ av,
    const float* __restrict__ Wp, const float* __restrict__ bp,
    const int* __restrict__ rowp, const uint2* __restrict__ edata,
    int colbase) {
    constexpr int FO = 8 * LPE;
    constexpr int SLOTS = 64 / LPE;
    const int wid = (blockIdx.x * (int)blockDim.x + (int)threadIdx.x) >> 6;
    if (wid >= N_NODES) return;
    const int lane = threadIdx.x & 63;
    const int e = lane / LPE, lp = lane % LPE;
    const int cb = lp * 8;

    __half2 wp0h[4], wp1h[4], wp2h[4], bph[4];
#pragma unroll
    for (int jj = 0; jj < 4; ++jj) {
        int c = cb + 2 * jj;
        wp0h[jj] = __floats2half2_rn(Wp[c], Wp[c + 1]);
        wp1h[jj] = __floats2half2_rn(Wp[FO + c], Wp[FO + c + 1]);
        wp2h[jj] = __floats2half2_rn(Wp[2 * FO + c], Wp[2 * FO + c + 1]);
        bph[jj]  = __floats2half2_rn(bp[c], bp[c + 1]);
    }
    float s[8], num[8];
#pragma unroll
    for (int j = 0; j < 8; ++j) { s[j] = 0.f; num[j] = 0.f; }

    const uint* avu = (const uint*)av;      // FO uints per node row
    const __half2 L2E = __float2half2_rn(LOG2E_F);
    const int beg = rowp[wid], end = rowp[wid + 1], last = end - 1;

    uint2 ed_c, ed_n;
    uint4 a_c, v_c, a_n, v_n;
    auto ld = [&](int idx, uint2& edo, uint4& a4, uint4& v4) {
        edo = edata[idx];
        const uint* rb = avu + (size_t)(edo.x & 0xFFFFu) * FO + (cb >> 1);
        a4 = *(const uint4*)rb;
        v4 = *(const uint4*)(rb + FO / 2);
    };

    ld(min(beg + e, last), ed_c, a_c, v_c);
    for (int base = beg; base < end; base += SLOTS) {
        ld(min(base + SLOTS + e, last), ed_n, a_n, v_n);
        const bool val = (base + e) < end;
        __half2 dz2 = __half2half2(__ushort_as_half((ushort)(ed_c.x >> 16)));
        __half2 dxy = *(__half2*)&ed_c.y;
        __half2 dx2 = __half2half2(__low2half(dxy));
        __half2 dy2 = __half2half2(__high2half(dxy));
        const uint* ap = (const uint*)&a_c;
        const uint* vp = (const uint*)&v_c;
#pragma unroll
        for (int jj = 0; jj < 4; ++jj) {
            uint am = val ? ap[jj] : 0xFC00FC00u;   // -inf,-inf
            __half2 d  = __hfma2(dx2, wp0h[jj], __hfma2(dy2, wp1h[jj], __hfma2(dz2, wp2h[jj], bph[jj])));
            __half2 a2 = __hfma2(d, L2E, *(const __half2*)&am);
            __half2 vd = __hadd2(*(const __half2*)&vp[jj], d);
            float pl = exp2f(__half2float(__low2half(a2)));
            float ph = exp2f(__half2float(__high2half(a2)));
            s[2 * jj]     += pl;
            s[2 * jj + 1] += ph;
            num[2 * jj]     = fmaf(pl, __half2float(__low2half(vd)),  num[2 * jj]);
            num[2 * jj + 1] = fmaf(ph, __half2float(__high2half(vd)), num[2 * jj + 1]);
        }
        ed_c = ed_n; a_c = a_n; v_c = v_n;
    }
    // reduce across edge slots
#pragma unroll
    for (int j = 0; j < 8; ++j) {
#pragma unroll
        for (int off = LPE; off < 64; off <<= 1) {
            s[j] += __shfl_xor(s[j], off);
            num[j] += __shfl_xor(num[j], off);
        }
    }
    if (e == 0) {
        ushort o[8];
#pragma unroll
        for (int j = 0; j < 8; ++j) {
            float xi = num[j] / s[j];
            xi = xi > 0.f ? xi : 0.01f * xi;
            __hip_bfloat16 b = __float2bfloat16(xi);
            o[j] = *(ushort*)&b;
        }
        ushort* dst = (ushort*)&h[(size_t)wid * HTOT + colbase + cb];
        *(uint4*)dst = *(uint4*)o;
    }
}

// ---------------- launch ----------------

extern "C" void kernel_launch(void* const* d_in, const int* in_sizes, int n_in,
                              void* d_out, int out_size, void* d_ws, size_t ws_size,
                              hipStream_t stream) {
    const float* x = (const float*)d_in[0];
    const int* ei = (const int*)d_in[1];
    const float *Wl[4], *Ws[4], *Wp[4], *bp[4];
    for (int i = 0; i < 4; ++i) {
        Wl[i] = (const float*)d_in[2 + 5 * i];
        Ws[i] = (const float*)d_in[3 + 5 * i];
        Wp[i] = (const float*)d_in[5 + 5 * i];
        bp[i] = (const float*)d_in[6 + 5 * i];
    }
    const float* Wm1 = (const float*)d_in[22];
    const float* bm1 = (const float*)d_in[23];
    const float* Wm2 = (const float*)d_in[24];
    const float* bm2 = (const float*)d_in[25];
    float* out = (float*)d_out;

    char* ws = (char*)d_ws;
    size_t off = 0;
    auto alloc = [&](size_t bytes) -> void* {
        void* p = ws + off;
        off += (bytes + 255) & ~(size_t)255;
        return p;
    };
    __hip_bfloat16* h = (__hip_bfloat16*)alloc((size_t)N_NODES * HTOT * 2);    // 40 MB
    __half* av = (__half*)alloc((size_t)N_NODES * 256 * 2);                    // 25.6 MB
    __hip_bfloat16* Wt0 = (__hip_bfloat16*)alloc((size_t)4096 * 2);
    __hip_bfloat16* Wt1 = (__hip_bfloat16*)alloc((size_t)12288 * 2);
    __hip_bfloat16* Wt2 = (__hip_bfloat16*)alloc((size_t)40960 * 2);
    __hip_bfloat16* Wt3 = (__hip_bfloat16*)alloc((size_t)73728 * 2);
    __hip_bfloat16* WtF = (__hip_bfloat16*)alloc((size_t)26624 * 2);
    int* deg = (int*)alloc((size_t)N_NODES * 4);
    int* rowp = (int*)alloc((size_t)(N_NODES + 1) * 4);
    int* cursor = (int*)alloc((size_t)N_NODES * 4);
    int* bsum = (int*)alloc((size_t)(NSCB + 1) * 4);
    uint2* edata = (uint2*)alloc((size_t)ET * 8);                              // 6.8 MB
    (void)ws_size; (void)n_in; (void)in_sizes; (void)out_size;

    PrepArgs pa;
    pa.x = x; pa.h = h; pa.deg = deg;
    pa.Ws0 = Ws[0]; pa.Wl0 = Wl[0];
    pa.Ws1 = Ws[1]; pa.Wl1 = Wl[1];
    pa.Ws2 = Ws[2]; pa.Wl2 = Wl[2];
    pa.Ws3 = Ws[3]; pa.Wl3 = Wl[3];
    pa.Wm1 = Wm1;
    pa.Wt0 = Wt0; pa.Wt1 = Wt1; pa.Wt2 = Wt2; pa.Wt3 = Wt3; pa.WtF = WtF;
    prep_kernel<<<(PREP_TOTAL + 255) / 256, 256, 0, stream>>>(pa);

    hist_kernel<<<(ET + 255) / 256, 256, 0, stream>>>(ei, deg);
    scan_p1<<<NSCB, 256, 0, stream>>>(deg, bsum);
    scan_p3<<<NSCB, 256, 0, stream>>>(deg, bsum, rowp, cursor);
    scatter_kernel<<<(ET + 255) / 256, 256, 0, stream>>>(ei, x, cursor, edata);

    const int M = N_NODES;
    const int GXP = (((M + 127) / 128 + 7) / 8) * 8;     // 392, multiple of 8
    const int nbn = (N_NODES + 3) / 4;                   // node-blocks (4 waves/block)
    __hip_bfloat16* Wts[4] = {Wt0, Wt1, Wt2, Wt3};
    for (int L = 0; L < 4; ++L) {
        const int K = INS_h[L], K32 = K32_h[L], fo = HO_h[L], n2 = 2 * fo;
        gemm3_kernel<false><<<GXP * (n2 / 64), 256, 0, stream>>>(
            h, HTOT, Wts[L], K32, nullptr, av, fo, M, K, GXP, nullptr, nullptr, nullptr);
        if (fo == 64)
            attn_kernel<8><<<nbn, 256, 0, stream>>>(h, av, Wp[L], bp[L], rowp, edata, K);
        else
            attn_kernel<16><<<nbn, 256, 0, stream>>>(h, av, Wp[L], bp[L], rowp, edata, K);
    }
    gemm3_kernel<true><<<GXP, 256, 0, stream>>>(h, HTOT, WtF, 416, bm1,
                                                nullptr, 0, M, 400, GXP, Wm2, bm2, out);
}

// Round 12
// 354.280 us; speedup vs baseline: 4.7471x; 1.0117x over previous
//
#include <hip/hip_runtime.h>
#include <hip/hip_bf16.h>
#include <hip/hip_fp16.h>
#include <math.h>

#define N_NODES 50000
#define N_EDGES 800000
#define ET (N_EDGES + N_NODES)
#define HTOT 400

#define SCAN_CHUNK 1024
#define NSCB ((N_NODES + SCAN_CHUNK - 1) / SCAN_CHUNK)   // 49

typedef __attribute__((ext_vector_type(4))) float f32x4;
typedef __attribute__((ext_vector_type(8))) short bf16x8;

static const int INS_h[4] = {16, 80, 144, 272};
static const int K32_h[4] = {32, 96, 160, 288};
static const int HO_h[4]  = {64, 64, 128, 128};

#define LOG2E_F 1.4426950408889634f

// ---------------- fused prep: copy_x + deg zero + all weight concats ----------------

struct PrepArgs {
    const float* x; __hip_bfloat16* h; int* deg;
    const float* Ws0; const float* Wl0;
    const float* Ws1; const float* Wl1;
    const float* Ws2; const float* Wl2;
    const float* Ws3; const float* Wl3;
    const float* Wm1;
    __hip_bfloat16* Wt0; __hip_bfloat16* Wt1; __hip_bfloat16* Wt2;
    __hip_bfloat16* Wt3; __hip_bfloat16* WtF;
};

__device__ inline void concat1(const float* __restrict__ W0, const float* __restrict__ W1,
                               int K, int K32, int fo, __hip_bfloat16* __restrict__ Wt, int i) {
    int c = i / K32, kk = i - c * K32;
    float v = 0.f;
    if (kk < K) v = (c < fo) ? W0[kk * fo + c] : W1[kk * fo + (c - fo)];
    Wt[i] = __float2bfloat16(v);
}

#define PREP_TOTAL 1007696

__global__ __launch_bounds__(256) void prep_kernel(PrepArgs a) {
    int i = blockIdx.x * 256 + threadIdx.x;
    if (i < 800000) {
        int n = i >> 4, c = i & 15;
        a.h[n * HTOT + c] = __float2bfloat16(a.x[i]);
        return;
    }
    i -= 800000;
    if (i < 50000) { a.deg[i] = 0; return; }
    i -= 50000;
    if (i < 4096)  { concat1(a.Ws0, a.Wl0, 16, 32, 64, a.Wt0, i); return; }
    i -= 4096;
    if (i < 12288) { concat1(a.Ws1, a.Wl1, 80, 96, 64, a.Wt1, i); return; }
    i -= 12288;
    if (i < 40960) { concat1(a.Ws2, a.Wl2, 144, 160, 128, a.Wt2, i); return; }
    i -= 40960;
    if (i < 73728) { concat1(a.Ws3, a.Wl3, 272, 288, 128, a.Wt3, i); return; }
    i -= 73728;
    if (i < 26624) {
        int c = i / 416, kk = i - c * 416;
        float v = (kk < 400) ? a.Wm1[kk * 64 + c] : 0.f;
        a.WtF[i] = __float2bfloat16(v);
    }
}

// ---------------- CSR build ----------------

__global__ void hist_kernel(const int* __restrict__ ei, int* __restrict__ deg) {
    int e = blockIdx.x * blockDim.x + threadIdx.x;
    if (e >= ET) return;
    int dst = (e < N_EDGES) ? ei[N_EDGES + e] : (e - N_EDGES);
    atomicAdd(&deg[dst], 1);
}

__global__ __launch_bounds__(256) void scan_p1(const int* __restrict__ deg,
                                               int* __restrict__ bsum) {
    __shared__ int red[256];
    const int b = blockIdx.x, t = threadIdx.x;
    const int base = b * SCAN_CHUNK + t * 4;
    int s = 0;
#pragma unroll
    for (int j = 0; j < 4; ++j) {
        int i = base + j;
        if (i < N_NODES) s += deg[i];
    }
    red[t] = s;
    __syncthreads();
    for (int off = 128; off > 0; off >>= 1) {
        if (t < off) red[t] += red[t + off];
        __syncthreads();
    }
    if (t == 0) bsum[b] = red[0];
}

// p3 with p2 folded in: each block redundantly wave-scans the 49 block sums.
__global__ __launch_bounds__(256) void scan_p3(const int* __restrict__ deg,
                                               const int* __restrict__ bsum,
                                               int* __restrict__ row_ptr,
                                               int* __restrict__ cursor) {
    __shared__ int ts[256];
    __shared__ int sb[2];
    const int b = blockIdx.x, t = threadIdx.x;
    if (t < 64) {
        int v = (t < NSCB) ? bsum[t] : 0;
        int inc = v;
#pragma unroll
        for (int off = 1; off < 64; off <<= 1) {
            int u = __shfl_up(inc, off);
            if (t >= off) inc += u;
        }
        if (t == b) sb[0] = inc - v;
        if (t == 63) sb[1] = inc;
    }
    const int base = b * SCAN_CHUNK + t * 4;
    int v[4];
    int s = 0;
#pragma unroll
    for (int j = 0; j < 4; ++j) {
        int i = base + j;
        v[j] = (i < N_NODES) ? deg[i] : 0;
        s += v[j];
    }
    ts[t] = s;
    __syncthreads();
    for (int off = 1; off < 256; off <<= 1) {
        int u = (t >= off) ? ts[t - off] : 0;
        __syncthreads();
        ts[t] += u;
        __syncthreads();
    }
    int excl = sb[0] + ts[t] - s;
#pragma unroll
    for (int j = 0; j < 4; ++j) {
        int i = base + j;
        if (i < N_NODES) {
            row_ptr[i] = excl;
            cursor[i] = excl;
            excl += v[j];
        }
    }
    if (b == 0 && t == 0) row_ptr[N_NODES] = sb[1];
}

// edata entry (8 B): x = src(16b) | dz_fp16(16b) ; y = half2(dx, dy)
__global__ void scatter_kernel(const int* __restrict__ ei, const float* __restrict__ x,
                               int* __restrict__ cursor, uint2* __restrict__ edata) {
    int e = blockIdx.x * blockDim.x + threadIdx.x;
    if (e >= ET) return;
    int src, dst;
    if (e < N_EDGES) { src = ei[e]; dst = ei[N_EDGES + e]; }
    else             { src = dst = e - N_EDGES; }
    int p = atomicAdd(&cursor[dst], 1);
    float4 pd = *(const float4*)&x[dst * 16];
    float4 ps = *(const float4*)&x[src * 16];
    __half dxh = __float2half(pd.x - ps.x);
    __half dyh = __float2half(pd.y - ps.y);
    __half dzh = __float2half(pd.z - ps.z);
    uint w0 = (uint)src | ((uint)__half_as_ushort(dzh) << 16);
    __half2 xy;
    xy.x = dxh; xy.y = dyh;
    edata[p] = make_uint2(w0, *(uint*)&xy);
}

// ---------------- bf16 MFMA GEMM (unchanged from round 11) ----------------

template <bool FUSE>
__global__ __launch_bounds__(256) void gemm3_kernel(
    const __hip_bfloat16* __restrict__ A, int lda,
    const __hip_bfloat16* __restrict__ Wt, int K32,
    const float* __restrict__ bias,
    __half* __restrict__ av, int fo,
    int M, int K, int GXP,
    const float* __restrict__ W2, const float* __restrict__ b2,
    float* __restrict__ out) {
    __shared__ float smemf[9728];
    ushort* sA = (ushort*)smemf;
    ushort* sB = (ushort*)smemf + 10240;
    const int t = threadIdx.x;
    const int bid = blockIdx.x;
    const int gxp = bid % GXP;
    const int gy = bid / GXP;
    const int r0 = gxp * 128, c0 = gy * 64;
    const int w = t >> 6, lane = t & 63;
    const int l15 = lane & 15, l4 = lane >> 4;

    f32x4 acc[2][4];
#pragma unroll
    for (int i = 0; i < 2; ++i)
#pragma unroll
        for (int j = 0; j < 4; ++j) acc[i][j] = (f32x4){0.f, 0.f, 0.f, 0.f};

    const int sr = t >> 2, sq = (t & 3) * 8;
    const int ar1 = min(r0 + sr, M - 1), ar2 = min(r0 + sr + 64, M - 1);
    const size_t a1b = (size_t)ar1 * lda, a2b = (size_t)ar2 * lda;
    const size_t wb = (size_t)(c0 + sr) * K32;
    const int nk = K32 >> 5;

    uint4 ga0, ga1, gb;
    const uint4 z4 = {0u, 0u, 0u, 0u};
    {
        const int kk = sq;
        const bool ok = kk < K;
        ga0 = ok ? *(const uint4*)(A + a1b + kk) : z4;
        ga1 = ok ? *(const uint4*)(A + a2b + kk) : z4;
        gb  = *(const uint4*)(Wt + wb + kk);
        *(uint4*)(sA + sr * 40 + sq) = ga0;
        *(uint4*)(sA + (sr + 64) * 40 + sq) = ga1;
        *(uint4*)(sB + sr * 40 + sq) = gb;
    }
    __syncthreads();

    int buf = 0;
    for (int kc = 0; kc < nk; ++kc) {
        const bool nx = (kc + 1) < nk;
        if (nx) {
            const int kk = (kc + 1) * 32 + sq;
            const bool ok = kk < K;
            ga0 = ok ? *(const uint4*)(A + a1b + kk) : z4;
            ga1 = ok ? *(const uint4*)(A + a2b + kk) : z4;
            gb  = *(const uint4*)(Wt + wb + kk);
        }
        const ushort* bA = sA + buf * 5120 + w * 1280;
        const ushort* bB = sB + buf * 2560;
        bf16x8 af[2], bfr[4];
#pragma unroll
        for (int i = 0; i < 2; ++i)
            af[i] = *(const bf16x8*)(bA + (i * 16 + l15) * 40 + l4 * 8);
#pragma unroll
        for (int j = 0; j < 4; ++j)
            bfr[j] = *(const bf16x8*)(bB + (j * 16 + l15) * 40 + l4 * 8);
#pragma unroll
        for (int i = 0; i < 2; ++i)
#pragma unroll
            for (int j = 0; j < 4; ++j)
                acc[i][j] = __builtin_amdgcn_mfma_f32_16x16x32_bf16(af[i], bfr[j], acc[i][j], 0, 0, 0);
        if (nx) {
            const int ob = buf ^ 1;
            *(uint4*)(sA + ob * 5120 + sr * 40 + sq) = ga0;
            *(uint4*)(sA + ob * 5120 + (sr + 64) * 40 + sq) = ga1;
            *(uint4*)(sB + ob * 2560 + sr * 40 + sq) = gb;
        }
        __syncthreads();
        buf ^= 1;
    }

    if (!FUSE) {
        const int n2 = 2 * fo;
#pragma unroll
        for (int i = 0; i < 2; ++i)
#pragma unroll
            for (int j = 0; j < 4; ++j)
#pragma unroll
                for (int p = 0; p < 4; ++p) {
                    int row = r0 + w * 32 + i * 16 + l4 * 4 + p;
                    int col = c0 + j * 16 + l15;
                    if (row < M) {
                        float vv = acc[i][j][p];
                        if (col < fo) vv *= -LOG2E_F;
                        av[(size_t)row * n2 + col] = __float2half(vv);
                    }
                }
    } else {
#pragma unroll
        for (int i = 0; i < 2; ++i)
#pragma unroll
            for (int j = 0; j < 4; ++j)
#pragma unroll
                for (int p = 0; p < 4; ++p) {
                    int lrow = w * 32 + i * 16 + l4 * 4 + p;
                    int col = j * 16 + l15;
                    smemf[lrow * 68 + col] = acc[i][j][p] + bias[col];
                }
        smemf[8704 + t] = W2[t];
        smemf[8704 + 256 + t] = W2[256 + t];
        __syncthreads();
        const int row = t >> 1, oc = (t & 1) * 4;
        f32x4 o = *(const f32x4*)&b2[oc];
#pragma unroll 8
        for (int k = 0; k < 64; ++k) {
            float a = smemf[row * 68 + k];
            o += a * *(const f32x4*)&smemf[8704 + k * 8 + oc];
        }
        const int grow = r0 + row;
        if (grow < M) *(f32x4*)&out[(size_t)grow * 8 + oc] = o;
    }
}

// ---------------- attention: SLOTS edge slots x LPE lanes; fp16 exp + fp16 slot accum ----------------
// av row: [0,fo) = -a_src*log2e (fp16), [fo,2fo) = v (fp16).
// p = exp2(delta*log2e - a_src*log2e); a_dst cancels in the per-dst softmax.
// Per-slot s/num accumulate in packed fp16 (few adds per slot); converted to fp32 once
// per node for the cross-slot shuffle reduction and final divide.

__device__ inline __half2 h2e2(__half2 a) {
    __half2 r;
    r.x = hexp2(__low2half(a));
    r.y = hexp2(__high2half(a));
    return r;
}

template <int LPE>   // lanes per edge: 8 (fo=64) or 16 (fo=128); 8 channels per lane
__global__ __launch_bounds__(256) void attn_kernel(
    __hip_bfloat16* __restrict__ h,
    const __half* __restrict__ av,
    const float* __restrict__ Wp, const float* __restrict__ bp,
    const int* __restrict__ rowp, const uint2* __restrict__ edata,
    int colbase) {
    constexpr int FO = 8 * LPE;
    constexpr int SLOTS = 64 / LPE;
    const int wid = (blockIdx.x * (int)blockDim.x + (int)threadIdx.x) >> 6;
    if (wid >= N_NODES) return;
    const int lane = threadIdx.x & 63;
    const int e = lane / LPE, lp = lane % LPE;
    const int cb = lp * 8;

    __half2 wp0h[4], wp1h[4], wp2h[4], bph[4];
#pragma unroll
    for (int jj = 0; jj < 4; ++jj) {
        int c = cb + 2 * jj;
        wp0h[jj] = __floats2half2_rn(Wp[c], Wp[c + 1]);
        wp1h[jj] = __floats2half2_rn(Wp[FO + c], Wp[FO + c + 1]);
        wp2h[jj] = __floats2half2_rn(Wp[2 * FO + c], Wp[2 * FO + c + 1]);
        bph[jj]  = __floats2half2_rn(bp[c], bp[c + 1]);
    }
    __half2 s2[4], n2v[4];
    const __half2 hz = __float2half2_rn(0.f);
#pragma unroll
    for (int j = 0; j < 4; ++j) { s2[j] = hz; n2v[j] = hz; }

    const uint* avu = (const uint*)av;
    const __half2 L2E = __float2half2_rn(LOG2E_F);
    const int beg = rowp[wid], end = rowp[wid + 1], last = end - 1;

    uint2 ed_c, ed_n;
    uint4 a_c, v_c, a_n, v_n;
    auto ld = [&](int idx, uint2& edo, uint4& a4, uint4& v4) {
        edo = edata[idx];
        const uint* rb = avu + (size_t)(edo.x & 0xFFFFu) * FO + (cb >> 1);
        a4 = *(const uint4*)rb;
        v4 = *(const uint4*)(rb + FO / 2);
    };

    ld(min(beg + e, last), ed_c, a_c, v_c);
    for (int base = beg; base < end; base += SLOTS) {
        ld(min(base + SLOTS + e, last), ed_n, a_n, v_n);
        const bool val = (base + e) < end;
        __half2 dz2 = __half2half2(__ushort_as_half((ushort)(ed_c.x >> 16)));
        __half2 dxy = *(__half2*)&ed_c.y;
        __half2 dx2 = __half2half2(__low2half(dxy));
        __half2 dy2 = __half2half2(__high2half(dxy));
        const uint* ap = (const uint*)&a_c;
        const uint* vp = (const uint*)&v_c;
#pragma unroll
        for (int jj = 0; jj < 4; ++jj) {
            uint am = val ? ap[jj] : 0xFC00FC00u;   // -inf,-inf -> p=0
            __half2 d  = __hfma2(dx2, wp0h[jj], __hfma2(dy2, wp1h[jj], __hfma2(dz2, wp2h[jj], bph[jj])));
            __half2 a2 = __hfma2(d, L2E, *(const __half2*)&am);
            __half2 vd = __hadd2(*(const __half2*)&vp[jj], d);
            __half2 p2 = h2e2(a2);
            s2[jj] = __hadd2(s2[jj], p2);
            n2v[jj] = __hfma2(p2, vd, n2v[jj]);
        }
        ed_c = ed_n; a_c = a_n; v_c = v_n;
    }
    // convert slot accumulators to fp32, then cross-slot reduce
    float s[8], num[8];
#pragma unroll
    for (int jj = 0; jj < 4; ++jj) {
        s[2 * jj]       = __half2float(__low2half(s2[jj]));
        s[2 * jj + 1]   = __half2float(__high2half(s2[jj]));
        num[2 * jj]     = __half2float(__low2half(n2v[jj]));
        num[2 * jj + 1] = __half2float(__high2half(n2v[jj]));
    }
#pragma unroll
    for (int j = 0; j < 8; ++j) {
#pragma unroll
        for (int off = LPE; off < 64; off <<= 1) {
            s[j] += __shfl_xor(s[j], off);
            num[j] += __shfl_xor(num[j], off);
        }
    }
    if (e == 0) {
        ushort o[8];
#pragma unroll
        for (int j = 0; j < 8; ++j) {
            float xi = num[j] / s[j];
            xi = xi > 0.f ? xi : 0.01f * xi;
            __hip_bfloat16 b = __float2bfloat16(xi);
            o[j] = *(ushort*)&b;
        }
        ushort* dst = (ushort*)&h[(size_t)wid * HTOT + colbase + cb];
        *(uint4*)dst = *(uint4*)o;
    }
}

// ---------------- launch ----------------

extern "C" void kernel_launch(void* const* d_in, const int* in_sizes, int n_in,
                              void* d_out, int out_size, void* d_ws, size_t ws_size,
                              hipStream_t stream) {
    const float* x = (const float*)d_in[0];
    const int* ei = (const int*)d_in[1];
    const float *Wl[4], *Ws[4], *Wp[4], *bp[4];
    for (int i = 0; i < 4; ++i) {
        Wl[i] = (const float*)d_in[2 + 5 * i];
        Ws[i] = (const float*)d_in[3 + 5 * i];
        Wp[i] = (const float*)d_in[5 + 5 * i];
        bp[i] = (const float*)d_in[6 + 5 * i];
    }
    const float* Wm1 = (const float*)d_in[22];
    const float* bm1 = (const float*)d_in[23];
    const float* Wm2 = (const float*)d_in[24];
    const float* bm2 = (const float*)d_in[25];
    float* out = (float*)d_out;

    char* ws = (char*)d_ws;
    size_t off = 0;
    auto alloc = [&](size_t bytes) -> void* {
        void* p = ws + off;
        off += (bytes + 255) & ~(size_t)255;
        return p;
    };
    __hip_bfloat16* h = (__hip_bfloat16*)alloc((size_t)N_NODES * HTOT * 2);
    __half* av = (__half*)alloc((size_t)N_NODES * 256 * 2);
    __hip_bfloat16* Wt0 = (__hip_bfloat16*)alloc((size_t)4096 * 2);
    __hip_bfloat16* Wt1 = (__hip_bfloat16*)alloc((size_t)12288 * 2);
    __hip_bfloat16* Wt2 = (__hip_bfloat16*)alloc((size_t)40960 * 2);
    __hip_bfloat16* Wt3 = (__hip_bfloat16*)alloc((size_t)73728 * 2);
    __hip_bfloat16* WtF = (__hip_bfloat16*)alloc((size_t)26624 * 2);
    int* deg = (int*)alloc((size_t)N_NODES * 4);
    int* rowp = (int*)alloc((size_t)(N_NODES + 1) * 4);
    int* cursor = (int*)alloc((size_t)N_NODES * 4);
    int* bsum = (int*)alloc((size_t)(NSCB + 1) * 4);
    uint2* edata = (uint2*)alloc((size_t)ET * 8);
    (void)ws_size; (void)n_in; (void)in_sizes; (void)out_size;

    PrepArgs pa;
    pa.x = x; pa.h = h; pa.deg = deg;
    pa.Ws0 = Ws[0]; pa.Wl0 = Wl[0];
    pa.Ws1 = Ws[1]; pa.Wl1 = Wl[1];
    pa.Ws2 = Ws[2]; pa.Wl2 = Wl[2];
    pa.Ws3 = Ws[3]; pa.Wl3 = Wl[3];
    pa.Wm1 = Wm1;
    pa.Wt0 = Wt0; pa.Wt1 = Wt1; pa.Wt2 = Wt2; pa.Wt3 = Wt3; pa.WtF = WtF;
    prep_kernel<<<(PREP_TOTAL + 255) / 256, 256, 0, stream>>>(pa);

    hist_kernel<<<(ET + 255) / 256, 256, 0, stream>>>(ei, deg);
    scan_p1<<<NSCB, 256, 0, stream>>>(deg, bsum);
    scan_p3<<<NSCB, 256, 0, stream>>>(deg, bsum, rowp, cursor);
    scatter_kernel<<<(ET + 255) / 256, 256, 0, stream>>>(ei, x, cursor, edata);

    const int M = N_NODES;
    const int GXP = (((M + 127) / 128 + 7) / 8) * 8;     // 392, multiple of 8
    const int nbn = (N_NODES + 3) / 4;
    __hip_bfloat16* Wts[4] = {Wt0, Wt1, Wt2, Wt3};
    for (int L = 0; L < 4; ++L) {
        const int K = INS_h[L], K32 = K32_h[L], fo = HO_h[L], n2 = 2 * fo;
        gemm3_kernel<false><<<GXP * (n2 / 64), 256, 0, stream>>>(
            h, HTOT, Wts[L], K32, nullptr, av, fo, M, K, GXP, nullptr, nullptr, nullptr);
        if (fo == 64)
            attn_kernel<8><<<nbn, 256, 0, stream>>>(h, av, Wp[L], bp[L], rowp, edata, K);
        else
            attn_kernel<16><<<nbn, 256, 0, stream>>>(h, av, Wp[L], bp[L], rowp, edata, K);
    }
    gemm3_kernel<true><<<GXP, 256, 0, stream>>>(h, HTOT, WtF, 416, bm1,
                                                nullptr, 0, M, 400, GXP, Wm2, bm2, out);
}